// Round 17
// baseline (658.985 us; speedup 1.0000x reference)
//
#include <hip/hip_runtime.h>
#include <hip/hip_fp16.h>

// GCN 3-layer: fp16 intermediates, f32 accum, MFMA GEMMs, zero-global-atomic CSR.
// NEW: column-sliced aggregation. H stored as [8][N][16] halves (slice = MFMA
// fragment col index). Agg runs 8 passes (pass = blockIdx&7 -> aligns with XCD
// round-robin), each gathering 32B/edge from a 3.2MB slice that fits per-XCD L2.
// 8 edges per load instruction (slot=lane>>3), masked clamp+fma, shfl_xor fold.
// ns[src] scaling folded into GEMM0 epilogue (row scale); agg output pre-scaled
// by ns[node] for the next layer (relu(x)*s == relu(x*s), s>0).

typedef _Float16 h8 __attribute__((ext_vector_type(8)));
typedef float f32x4 __attribute__((ext_vector_type(4)));

#define HWORDS 25024   // ceil(100000/4), = 391*64 exactly
#define NHS 32         // src histogram chunks
#define NHD 256        // dst histogram chunks

// ---------------- pre: {32 src hist} | {256 dst hist} | {W -> fp16 transposed} --------
__global__ __launch_bounds__(256) void k_pre(const int* __restrict__ src,
                                             const int* __restrict__ dst, int E,
                                             unsigned* __restrict__ histo_s,
                                             unsigned* __restrict__ histo_d,
                                             const float* __restrict__ W0,
                                             const float* __restrict__ W1,
                                             const float* __restrict__ W2,
                                             __half* __restrict__ Wt0,
                                             __half* __restrict__ Wt1,
                                             __half* __restrict__ Wt2) {
    __shared__ unsigned H[HWORDS];
    const int b = blockIdx.x;
    if (b < NHS + NHD) {
        const bool isS = b < NHS;
        const int c = isS ? b : b - NHS;
        const int NC = isS ? NHS : NHD;
        const int* arr = isS ? src : dst;
        unsigned* outp = (isS ? histo_s : histo_d) + (size_t)c * HWORDS;
        for (int i = threadIdx.x; i < HWORDS; i += 256) H[i] = 0;
        __syncthreads();
        const int perB = ((E + NC - 1) / NC + 3) & ~3;
        const int e0 = min(c * perB, E), e1 = min(e0 + perB, E);
        int i = e0 + threadIdx.x * 4;
        for (; i + 3 < e1; i += 1024) {
            int4 s4 = *(const int4*)(arr + i);
            atomicAdd(&H[s4.x >> 2], 1u << ((s4.x & 3) * 8));
            atomicAdd(&H[s4.y >> 2], 1u << ((s4.y & 3) * 8));
            atomicAdd(&H[s4.z >> 2], 1u << ((s4.z & 3) * 8));
            atomicAdd(&H[s4.w >> 2], 1u << ((s4.w & 3) * 8));
        }
        for (; i < e1; ++i) {
            int s = arr[i];
            atomicAdd(&H[s >> 2], 1u << ((s & 3) * 8));
        }
        __syncthreads();
        for (int i2 = threadIdx.x; i2 < HWORDS; i2 += 256) outp[i2] = H[i2];
    } else {
        int j0 = (b - NHS - NHD) * 20480;
        for (int j = j0 + threadIdx.x; j < j0 + 20480; j += 256) {
            if (j < 16384) {
                int nn = j >> 7, k = j & 127;
                Wt0[j] = __float2half(W0[k * 128 + nn]);
            } else if (j < 32768) {
                int i2 = j - 16384;
                int nn = i2 >> 7, k = i2 & 127;
                Wt1[i2] = __float2half(W1[k * 128 + nn]);
            } else if (j < 40960) {
                int i2 = j - 32768;
                int nn = i2 >> 7, k = i2 & 127;
                Wt2[i2] = __float2half(W2[k * 64 + nn]);
            }
        }
    }
}

// ---------------- scan1: dst-prefix transform (in place) + norms + block-local scan ----
__global__ __launch_bounds__(256) void k_scan1(const unsigned* __restrict__ histo_s,
                                               unsigned* __restrict__ histo_d,
                                               int* __restrict__ rp,
                                               int* __restrict__ bsum,
                                               float* __restrict__ ns,
                                               float* __restrict__ nd, int n) {
    __shared__ unsigned di4[64];
    __shared__ unsigned do4[64];
    const int tid = threadIdx.x, lane = tid & 63, wid = tid >> 6;
    if (tid < 64) {
        const int w = blockIdx.x * 64 + tid;
        unsigned run4 = 0;
#pragma unroll 8
        for (int b = 0; b < NHD; ++b) {
            unsigned c4 = histo_d[(size_t)b * HWORDS + w];
            histo_d[(size_t)b * HWORDS + w] = run4;
            run4 += c4;
        }
        di4[tid] = run4;
        unsigned s4 = 0;
#pragma unroll 8
        for (int b = 0; b < NHS; ++b) s4 += histo_s[(size_t)b * HWORDS + w];
        do4[tid] = s4;
    }
    __syncthreads();
    int i = blockIdx.x * 256 + tid;
    int v = 0;
    if (i < n) {
        int sh = (tid & 3) * 8;
        v = (di4[tid >> 2] >> sh) & 255;
        int dgo = (do4[tid >> 2] >> sh) & 255;
        nd[i] = rsqrtf((float)max(v, 1));
        ns[i] = rsqrtf((float)max(dgo, 1));
    }
    int x = v;
#pragma unroll
    for (int off = 1; off < 64; off <<= 1) {
        int t = __shfl_up(x, off, 64);
        if (lane >= off) x += t;
    }
    __shared__ int ws[4];
    if (lane == 63) ws[wid] = x;
    __syncthreads();
    int wo = 0;
    for (int k = 0; k < wid; ++k) wo += ws[k];
    int incl = wo + x;
    if (i < n) rp[i] = incl - v;
    if (tid == 255) bsum[blockIdx.x] = incl;
}

__global__ __launch_bounds__(512) void k_scan2(int* __restrict__ bsum, int nb,
                                               int* __restrict__ rpN) {
    __shared__ int s[512];
    const int tid = threadIdx.x;
    int v = (tid < nb) ? bsum[tid] : 0;
    s[tid] = v;
    __syncthreads();
    for (int off = 1; off < 512; off <<= 1) {
        int t = (tid >= off) ? s[tid - off] : 0;
        __syncthreads();
        s[tid] += t;
        __syncthreads();
    }
    if (tid < nb) bsum[tid] = s[tid] - v;
    if (tid == nb - 1) *rpN = v;
}

// ---------------- scatter2: rank via LDS byte-atomic, place edges -----------------------
__global__ __launch_bounds__(256) void k_scatter2(const int* __restrict__ src,
                                                  const int* __restrict__ dst, int E,
                                                  const int* __restrict__ rp,
                                                  const int* __restrict__ bsum,
                                                  const unsigned* __restrict__ pfx_all,
                                                  int* __restrict__ csr) {
    __shared__ unsigned Hd[HWORDS];
    for (int i = threadIdx.x; i < HWORDS; i += 256) Hd[i] = 0;
    __syncthreads();
    const int c = blockIdx.x;
    const int perB = ((E + NHD - 1) / NHD + 3) & ~3;
    const int e0 = min(c * perB, E), e1 = min(e0 + perB, E);
    const unsigned* pfx = pfx_all + (size_t)c * HWORDS;
    int i = e0 + threadIdx.x * 4;
    for (; i + 3 < e1; i += 1024) {
        int4 d4 = *(const int4*)(dst + i);
        int4 s4 = *(const int4*)(src + i);
#define PROC(dd, ss)                                                            \
        {                                                                       \
            int sh = ((dd) & 3) * 8;                                            \
            int base = rp[dd] + bsum[(dd) >> 8] +                               \
                       (int)((pfx[(dd) >> 2] >> sh) & 255u);                    \
            unsigned old = atomicAdd(&Hd[(dd) >> 2], 1u << sh);                 \
            csr[base + (int)((old >> sh) & 255u)] = (ss);                       \
        }
        PROC(d4.x, s4.x) PROC(d4.y, s4.y) PROC(d4.z, s4.z) PROC(d4.w, s4.w)
    }
    for (; i < e1; ++i) PROC(dst[i], src[i])
#undef PROC
}

// ---------------- GEMM body: Cs (slice layout [BN/16][n][16]) = A[n,128] @ Wt^T ---------
// v_mfma_f32_16x16x32_f16; frag mapping verified round-6. NSROW: scale row by ns.
template <int BN, bool F32A, bool NSROW>
__device__ __forceinline__ void gemm_body(const void* __restrict__ Ap,
                                          const __half* __restrict__ Wt,
                                          const float* __restrict__ nsr,
                                          __half* __restrict__ Cs, int n, int gb) {
    constexpr int K = 128, BM = 128, LDR = K + 8;
    __shared__ __half Al[BM * LDR];
    __shared__ __half Bl[BN * LDR];
    const int tid = threadIdx.x;
    const int row0 = gb * BM;
    if (F32A) {
        const float* A = (const float*)Ap;  // normal layout [n][128] f32
#pragma unroll
        for (int q = 0; q < 16; ++q) {
            int fi = q * 256 + tid;
            int r = fi >> 5, c = (fi & 31) * 4;
            int gr = row0 + r;
            float4 v = make_float4(0.f, 0.f, 0.f, 0.f);
            if (gr < n) v = *(const float4*)(A + (size_t)gr * K + c);
            __half2 h0 = __floats2half2_rn(v.x, v.y);
            __half2 h1 = __floats2half2_rn(v.z, v.w);
            uint2 pk = make_uint2(*(unsigned*)&h0, *(unsigned*)&h1);
            *(uint2*)&Al[r * LDR + c] = pk;
        }
    } else {
        const __half* A = (const __half*)Ap;  // slice layout [8][n][16] fp16
#pragma unroll
        for (int q = 0; q < 8; ++q) {
            int idx = q * 256 + tid;
            int slice = idx >> 8, rr = idx & 255;
            int r = rr >> 1, off = (rr & 1) * 8;
            int gr = row0 + r;
            float4 v = make_float4(0.f, 0.f, 0.f, 0.f);
            if (gr < n) v = *(const float4*)(A + ((size_t)slice * n + gr) * 16 + off);
            *(float4*)&Al[r * LDR + slice * 16 + off] = v;
        }
    }
#pragma unroll
    for (int q = 0; q < BN / 16; ++q) {
        int fi = q * 256 + tid;
        int r = fi >> 4, c = (fi & 15) * 8;
        *(float4*)&Bl[r * LDR + c] = *(const float4*)(Wt + (size_t)r * K + c);
    }
    __syncthreads();
    const int wid = tid >> 6, lane = tid & 63;
    const int lo = lane & 15, hi = lane >> 4;
    constexpr int NC = BN / 16;
    f32x4 acc[2][NC];
#pragma unroll
    for (int t = 0; t < 2; ++t)
#pragma unroll
        for (int c = 0; c < NC; ++c) acc[t][c] = (f32x4){0.f, 0.f, 0.f, 0.f};
#pragma unroll
    for (int kc = 0; kc < 4; ++kc) {
        h8 aF[2];
#pragma unroll
        for (int t = 0; t < 2; ++t)
            aF[t] = *(const h8*)&Al[(32 * wid + 16 * t + lo) * LDR + 32 * kc + 8 * hi];
#pragma unroll
        for (int c = 0; c < NC; ++c) {
            h8 bF = *(const h8*)&Bl[(16 * c + lo) * LDR + 32 * kc + 8 * hi];
#pragma unroll
            for (int t = 0; t < 2; ++t)
                acc[t][c] = __builtin_amdgcn_mfma_f32_16x16x32_f16(aF[t], bF, acc[t][c], 0, 0, 0);
        }
    }
    // store slice layout: col = 16c + lo -> Cs[(c*n + gr)*16 + lo]
#pragma unroll
    for (int t = 0; t < 2; ++t) {
#pragma unroll
        for (int j = 0; j < 4; ++j) {
            int gr = row0 + 32 * wid + 16 * t + 4 * hi + j;
            if (gr < n) {
                float s = NSROW ? nsr[gr] : 1.f;
#pragma unroll
                for (int c = 0; c < NC; ++c)
                    Cs[((size_t)c * n + gr) * 16 + lo] = __float2half(acc[t][c][j] * s);
            }
        }
    }
}

template <int BN, bool F32A, bool NSROW>
__global__ __launch_bounds__(256) void k_gemm(const void* __restrict__ A,
                                              const __half* __restrict__ Wt,
                                              const float* __restrict__ nsr,
                                              __half* __restrict__ Cs, int n) {
    gemm_body<BN, F32A, NSROW>(A, Wt, nsr, Cs, n, blockIdx.x);
}

// ---------------- agg, 128-col, pass-split (8 passes, pass = blockIdx&7) ----------------
// Hs: [8][n][16] halves. 8 edges/load-instr: slot=lane>>3 picks edge, sub=lane&7
// picks 4B of 32B row. Masked clamp+fma. Out: Xs slice layout, relu + ns[node].
__global__ __launch_bounds__(256) void k_agg128p(const __half* __restrict__ Hs,
                                                 const int* __restrict__ rp,
                                                 const int* __restrict__ bsum,
                                                 const int* __restrict__ cs,
                                                 const float* __restrict__ nd,
                                                 const float* __restrict__ ns,
                                                 const float* __restrict__ b,
                                                 __half* __restrict__ Xs, int n) {
    const int wid = threadIdx.x >> 6, lane = threadIdx.x & 63;
    const int p = blockIdx.x & 7;
    const int node = (blockIdx.x >> 3) * 4 + wid;
    if (node >= n) return;
    const int slot = lane >> 3, sub = lane & 7;
    const int beg = rp[node] + bsum[node >> 8];
    const int end = rp[node + 1] + bsum[(node + 1) >> 8];
    const __half* Hp = Hs + (size_t)p * n * 16;
    float2 a0 = make_float2(0.f, 0.f), a1 = a0;
    for (int e = beg; e < end; e += 16) {
        int i0 = e + slot, i1 = e + 8 + slot;
        int r0 = (i0 < end) ? i0 : beg;
        int r1 = (i1 < end) ? i1 : beg;
        float w0 = (i0 < end) ? 1.f : 0.f;
        float w1 = (i1 < end) ? 1.f : 0.f;
        int s0 = cs[r0], s1 = cs[r1];
        float f0 = *(const float*)(Hp + (size_t)s0 * 16 + sub * 2);
        float f1 = *(const float*)(Hp + (size_t)s1 * 16 + sub * 2);
        float2 v0 = __half22float2(*(__half2*)&f0);
        float2 v1 = __half22float2(*(__half2*)&f1);
        a0.x = fmaf(v0.x, w0, a0.x); a0.y = fmaf(v0.y, w0, a0.y);
        a1.x = fmaf(v1.x, w1, a1.x); a1.y = fmaf(v1.y, w1, a1.y);
    }
    float ax = a0.x + a1.x, ay = a0.y + a1.y;
    ax += __shfl_xor(ax, 8, 64);  ay += __shfl_xor(ay, 8, 64);
    ax += __shfl_xor(ax, 16, 64); ay += __shfl_xor(ay, 16, 64);
    ax += __shfl_xor(ax, 32, 64); ay += __shfl_xor(ay, 32, 64);
    if (slot == 0) {
        const float sc = nd[node], sn = ns[node];
        const int col = p * 16 + sub * 2;
        float ox = fmaxf(ax * sc + b[col], 0.f) * sn;
        float oy = fmaxf(ay * sc + b[col + 1], 0.f) * sn;
        __half2 h = __floats2half2_rn(ox, oy);
        *(__half2*)(Xs + ((size_t)p * n + node) * 16 + sub * 2) = h;
    }
}

// ---------------- agg, 64-col, pass-split (4 passes), f32 out, no relu/ns ---------------
__global__ __launch_bounds__(256) void k_agg64p(const __half* __restrict__ Hs,  // [4][n][16]
                                                const int* __restrict__ rp,
                                                const int* __restrict__ bsum,
                                                const int* __restrict__ cs,
                                                const float* __restrict__ nd,
                                                const float* __restrict__ b,
                                                float* __restrict__ out, int n) {
    const int wid = threadIdx.x >> 6, lane = threadIdx.x & 63;
    const int p = blockIdx.x & 3;
    const int node = (blockIdx.x >> 2) * 4 + wid;
    if (node >= n) return;
    const int slot = lane >> 3, sub = lane & 7;
    const int beg = rp[node] + bsum[node >> 8];
    const int end = rp[node + 1] + bsum[(node + 1) >> 8];
    const __half* Hp = Hs + (size_t)p * n * 16;
    float2 a0 = make_float2(0.f, 0.f), a1 = a0;
    for (int e = beg; e < end; e += 16) {
        int i0 = e + slot, i1 = e + 8 + slot;
        int r0 = (i0 < end) ? i0 : beg;
        int r1 = (i1 < end) ? i1 : beg;
        float w0 = (i0 < end) ? 1.f : 0.f;
        float w1 = (i1 < end) ? 1.f : 0.f;
        int s0 = cs[r0], s1 = cs[r1];
        float f0 = *(const float*)(Hp + (size_t)s0 * 16 + sub * 2);
        float f1 = *(const float*)(Hp + (size_t)s1 * 16 + sub * 2);
        float2 v0 = __half22float2(*(__half2*)&f0);
        float2 v1 = __half22float2(*(__half2*)&f1);
        a0.x = fmaf(v0.x, w0, a0.x); a0.y = fmaf(v0.y, w0, a0.y);
        a1.x = fmaf(v1.x, w1, a1.x); a1.y = fmaf(v1.y, w1, a1.y);
    }
    float ax = a0.x + a1.x, ay = a0.y + a1.y;
    ax += __shfl_xor(ax, 8, 64);  ay += __shfl_xor(ay, 8, 64);
    ax += __shfl_xor(ax, 16, 64); ay += __shfl_xor(ay, 16, 64);
    ax += __shfl_xor(ax, 32, 64); ay += __shfl_xor(ay, 32, 64);
    if (slot == 0) {
        const float sc = nd[node];
        const int col = p * 16 + sub * 2;
        float2 o = make_float2(ax * sc + b[col], ay * sc + b[col + 1]);
        *(float2*)(out + (size_t)node * 64 + col) = o;
    }
}

extern "C" void kernel_launch(void* const* d_in, const int* in_sizes, int n_in,
                              void* d_out, int out_size, void* d_ws, size_t ws_size,
                              hipStream_t stream) {
    const float* feat = (const float*)d_in[0];
    const int* ei = (const int*)d_in[1];
    const float* W0 = (const float*)d_in[2];
    const float* b0 = (const float*)d_in[3];
    const float* W1 = (const float*)d_in[4];
    const float* b1 = (const float*)d_in[5];
    const float* W2 = (const float*)d_in[6];
    const float* b2 = (const float*)d_in[7];
    float* out = (float*)d_out;

    const int N = in_sizes[0] / 128;  // 100000
    const int E = in_sizes[1] / 2;    // 1600000
    const int* src = ei;
    const int* dst = ei + E;
    const int NB = (N + 255) / 256;   // 391 scan blocks

    // workspace layout (16B-aligned chunks)
    char* w = (char*)d_ws;
    float* norm_src = (float*)w; w += (size_t)N * 4;
    float* norm_dst = (float*)w; w += (size_t)N * 4;
    unsigned* histo_s = (unsigned*)w; w += (size_t)NHS * HWORDS * 4;
    unsigned* histo_d = (unsigned*)w; w += (size_t)NHD * HWORDS * 4;
    int* rp    = (int*)w;        w += ((size_t)(N + 1) * 4 + 15) / 16 * 16;
    int* bsum  = (int*)w;        w += 512 * 4;
    int* csr   = (int*)w;        w += (size_t)E * 4;
    __half* Wt0 = (__half*)w;    w += 128 * 128 * 2;
    __half* Wt1 = (__half*)w;    w += 128 * 128 * 2;
    __half* Wt2 = (__half*)w;    w += 128 * 64 * 2;
    __half* Hb = (__half*)w;     w += (size_t)N * 128 * 2;  // GEMM out, slice layout
    __half* Xb = (__half*)w;     w += (size_t)N * 128 * 2;  // agg out, slice layout

    const int GB = (N + 127) / 128;        // 782 GEMM blocks
    const int nb4 = (N + 3) / 4;           // node blocks (4 nodes/block)

    // CSR build, no global atomics
    k_pre<<<NHS + NHD + 2, 256, 0, stream>>>(src, dst, E, histo_s, histo_d,
                                             W0, W1, W2, Wt0, Wt1, Wt2);
    k_scan1<<<NB, 256, 0, stream>>>(histo_s, histo_d, rp, bsum, norm_src, norm_dst, N);
    k_scan2<<<1, 512, 0, stream>>>(bsum, NB, rp + N);
    k_scatter2<<<NHD, 256, 0, stream>>>(src, dst, E, rp, bsum, histo_d, csr);

    // layer 0: H = (feat @ W0) * ns_row  (slice layout)
    k_gemm<128, true, true><<<GB, 256, 0, stream>>>(feat, Wt0, norm_src, Hb, N);
    k_agg128p<<<nb4 * 8, 256, 0, stream>>>(Hb, rp, bsum, csr, norm_dst, norm_src, b0, Xb, N);
    // layer 1
    k_gemm<128, false, false><<<GB, 256, 0, stream>>>(Xb, Wt1, nullptr, Hb, N);
    k_agg128p<<<nb4 * 8, 256, 0, stream>>>(Hb, rp, bsum, csr, norm_dst, norm_src, b1, Xb, N);
    // layer 2 (BN=64, no relu, f32 out, normal layout)
    k_gemm<64, false, false><<<GB, 256, 0, stream>>>(Xb, Wt2, nullptr, Hb, N);
    k_agg64p<<<nb4 * 4, 256, 0, stream>>>(Hb, rp, bsum, csr, norm_dst, b2, out, N);
}

// Round 18
// 357.549 us; speedup vs baseline: 1.8431x; 1.8431x over previous
//
#include <hip/hip_runtime.h>
#include <hip/hip_fp16.h>

// GCN 3-layer: fp16 intermediates, f32 accum, MFMA GEMMs, zero-global-atomic CSR.
// Round-16 structure (proven 353.6us) + GEMM0 fused into k_pre (in-kernel W0
// transpose, LDS union with histogram buffer) + 4-way parallel scan1 chunk loop.
// Agg: wave/node, uniform masked 8-wide rounds, scalarized csr index loads.
// Math: (x*ns)@W == (x@W)*ns_row; layer-0 folds ns[src] into the gather (fma),
// later layers pre-scale the agg output by ns (relu(x)*s == relu(x*s), s>0).

typedef _Float16 h8 __attribute__((ext_vector_type(8)));
typedef float f32x4 __attribute__((ext_vector_type(4)));

#define HWORDS 25024   // ceil(100000/4), = 391*64 exactly
#define NHS 32         // src histogram chunks
#define NHD 256        // dst histogram chunks

// ---------------- shared GEMM body: C[n,BN](fp16) = A[n,128] @ W ----------------
// v_mfma_f32_16x16x32_f16; A/B frag = 8 halves at k=8*(lane>>4), row/col=lane&15;
// C/D: col=lane&15, row=(lane>>4)*4+reg (guide m89-verified; round-6 validated).
// TRANSW: W is f32 [K][BN] row-major, transposed+cast to LDS in-kernel (round-8
// proven). Else W is pre-transposed fp16 [BN][K].
template <int BN, bool F32A, bool TRANSW>
__device__ __forceinline__ void gemm_body(const void* __restrict__ Ap,
                                          const void* __restrict__ Wp,
                                          __half* Al, __half* Bl,
                                          __half* __restrict__ C, int n, int gb) {
    constexpr int K = 128, BM = 128, LDR = K + 8;  // halves; 272B rows
    const int tid = threadIdx.x;
    const int row0 = gb * BM;
    if (F32A) {
        const float* A = (const float*)Ap;
#pragma unroll
        for (int q = 0; q < 16; ++q) {
            int fi = q * 256 + tid;
            int r = fi >> 5, c = (fi & 31) * 4;
            int gr = row0 + r;
            float4 v = make_float4(0.f, 0.f, 0.f, 0.f);
            if (gr < n) v = *(const float4*)(A + (size_t)gr * K + c);
            __half2 h0 = __floats2half2_rn(v.x, v.y);
            __half2 h1 = __floats2half2_rn(v.z, v.w);
            uint2 pk = make_uint2(*(unsigned*)&h0, *(unsigned*)&h1);
            *(uint2*)&Al[r * LDR + c] = pk;
        }
    } else {
        const __half* A = (const __half*)Ap;
#pragma unroll
        for (int q = 0; q < 8; ++q) {
            int fi = q * 256 + tid;
            int r = fi >> 4, c = (fi & 15) * 8;
            int gr = row0 + r;
            float4 v = make_float4(0.f, 0.f, 0.f, 0.f);
            if (gr < n) v = *(const float4*)(A + (size_t)gr * K + c);
            *(float4*)&Al[r * LDR + c] = v;
        }
    }
    if (TRANSW) {
        const float* W = (const float*)Wp;  // f32 [K][BN]
#pragma unroll
        for (int q = 0; q < (K * BN / 4) / 256; ++q) {
            int fi = q * 256 + tid;
            int k = fi / (BN / 4), n4 = (fi % (BN / 4)) * 4;
            float4 v = *(const float4*)(W + (size_t)k * BN + n4);
            Bl[(n4 + 0) * LDR + k] = __float2half(v.x);
            Bl[(n4 + 1) * LDR + k] = __float2half(v.y);
            Bl[(n4 + 2) * LDR + k] = __float2half(v.z);
            Bl[(n4 + 3) * LDR + k] = __float2half(v.w);
        }
    } else {
        const __half* Wt = (const __half*)Wp;  // fp16 [BN][K]
#pragma unroll
        for (int q = 0; q < BN / 16; ++q) {
            int fi = q * 256 + tid;
            int r = fi >> 4, c = (fi & 15) * 8;
            *(float4*)&Bl[r * LDR + c] = *(const float4*)(Wt + (size_t)r * K + c);
        }
    }
    __syncthreads();
    const int wid = tid >> 6, lane = tid & 63;
    const int lo = lane & 15, hi = lane >> 4;
    constexpr int NC = BN / 16;
    f32x4 acc[2][NC];
#pragma unroll
    for (int t = 0; t < 2; ++t)
#pragma unroll
        for (int c = 0; c < NC; ++c) acc[t][c] = (f32x4){0.f, 0.f, 0.f, 0.f};
#pragma unroll
    for (int kc = 0; kc < 4; ++kc) {
        h8 aF[2];
#pragma unroll
        for (int t = 0; t < 2; ++t)
            aF[t] = *(const h8*)&Al[(32 * wid + 16 * t + lo) * LDR + 32 * kc + 8 * hi];
#pragma unroll
        for (int c = 0; c < NC; ++c) {
            h8 bF = *(const h8*)&Bl[(16 * c + lo) * LDR + 32 * kc + 8 * hi];
#pragma unroll
            for (int t = 0; t < 2; ++t)
                acc[t][c] = __builtin_amdgcn_mfma_f32_16x16x32_f16(aF[t], bF, acc[t][c], 0, 0, 0);
        }
    }
#pragma unroll
    for (int t = 0; t < 2; ++t) {
#pragma unroll
        for (int j = 0; j < 4; ++j) {
            int gr = row0 + 32 * wid + 16 * t + 4 * hi + j;
            if (gr < n) {
#pragma unroll
                for (int c = 0; c < NC; ++c)
                    C[(size_t)gr * BN + 16 * c + lo] = __float2half(acc[t][c][j]);
            }
        }
    }
}

// ---------------- fused pre: {GEMM0} | {32 src hist} | {256 dst hist} | {Wt1/Wt2} ------
__global__ __launch_bounds__(256) void k_pre(
        const float* __restrict__ feat, const float* __restrict__ W0,
        __half* __restrict__ Hb, int n, int GB,
        const int* __restrict__ src, const int* __restrict__ dst, int E,
        unsigned* __restrict__ histo_s, unsigned* __restrict__ histo_d,
        const float* __restrict__ W1, const float* __restrict__ W2,
        __half* __restrict__ Wt1, __half* __restrict__ Wt2) {
    __shared__ __align__(16) char smem[HWORDS * 4];  // 100096 B union
    const int b = blockIdx.x;
    if (b < GB) {
        // GEMM0: Hb = feat @ W0 (in-kernel W0 transpose; Al/Bl carved from smem)
        __half* Al = (__half*)smem;
        __half* Bl = (__half*)(smem + 128 * 136 * 2);
        gemm_body<128, true, true>(feat, W0, Al, Bl, Hb, n, b);
    } else if (b < GB + NHS + NHD) {
        unsigned* H = (unsigned*)smem;
        const int hb = b - GB;
        const bool isS = hb < NHS;
        const int c = isS ? hb : hb - NHS;
        const int NC = isS ? NHS : NHD;
        const int* arr = isS ? src : dst;
        unsigned* outp = (isS ? histo_s : histo_d) + (size_t)c * HWORDS;
        for (int i = threadIdx.x; i < HWORDS; i += 256) H[i] = 0;
        __syncthreads();
        const int perB = ((E + NC - 1) / NC + 3) & ~3;
        const int e0 = min(c * perB, E), e1 = min(e0 + perB, E);
        int i = e0 + threadIdx.x * 4;
        for (; i + 3 < e1; i += 1024) {
            int4 s4 = *(const int4*)(arr + i);
            atomicAdd(&H[s4.x >> 2], 1u << ((s4.x & 3) * 8));
            atomicAdd(&H[s4.y >> 2], 1u << ((s4.y & 3) * 8));
            atomicAdd(&H[s4.z >> 2], 1u << ((s4.z & 3) * 8));
            atomicAdd(&H[s4.w >> 2], 1u << ((s4.w & 3) * 8));
        }
        for (; i < e1; ++i) {
            int s = arr[i];
            atomicAdd(&H[s >> 2], 1u << ((s & 3) * 8));
        }
        __syncthreads();
        for (int i2 = threadIdx.x; i2 < HWORDS; i2 += 256) outp[i2] = H[i2];
    } else {
        int j0 = (b - GB - NHS - NHD) * 12288;
        for (int j = j0 + threadIdx.x; j < j0 + 12288; j += 256) {
            if (j < 16384) {
                int nn = j >> 7, k = j & 127;
                Wt1[j] = __float2half(W1[k * 128 + nn]);
            } else if (j < 24576) {
                int i2 = j - 16384;
                int nn = i2 >> 7, k = i2 & 127;
                Wt2[i2] = __float2half(W2[k * 64 + nn]);
            }
        }
    }
}

// ---------------- scan1: 4-way parallel dst-prefix transform + norms + block scan ------
__global__ __launch_bounds__(256) void k_scan1(const unsigned* __restrict__ histo_s,
                                               unsigned* __restrict__ histo_d,
                                               int* __restrict__ rp,
                                               int* __restrict__ bsum,
                                               float* __restrict__ ns,
                                               float* __restrict__ nd, int n) {
    __shared__ unsigned qsd[4][64];  // quarter sums (dst), packed bytes
    __shared__ unsigned qss[4][64];  // quarter sums (src)
    __shared__ unsigned di4[64];     // packed deg_i for this block's 256 nodes
    __shared__ unsigned do4[64];     // packed deg_o
    const int tid = threadIdx.x, lane = tid & 63, q = tid >> 6;
    const int w = blockIdx.x * 64 + lane;  // word index (4 nodes); 391*64 == HWORDS
    // pass 1: quarter sums (wave q handles chunks [q*64,(q+1)*64) of dst, [q*8,..) of src)
    {
        unsigned s = 0;
#pragma unroll 8
        for (int b = q * 64; b < (q + 1) * 64; ++b)
            s += histo_d[(size_t)b * HWORDS + w];
        qsd[q][lane] = s;
        unsigned s2 = 0;
#pragma unroll
        for (int b = q * 8; b < (q + 1) * 8; ++b)
            s2 += histo_s[(size_t)b * HWORDS + w];
        qss[q][lane] = s2;
    }
    __syncthreads();
    if (q == 0) {
        di4[lane] = qsd[0][lane] + qsd[1][lane] + qsd[2][lane] + qsd[3][lane];
        do4[lane] = qss[0][lane] + qss[1][lane] + qss[2][lane] + qss[3][lane];
    }
    // pass 2: write exclusive chunk prefixes with quarter base
    {
        unsigned run = 0;
        for (int k = 0; k < q; ++k) run += qsd[k][lane];
#pragma unroll 8
        for (int b = q * 64; b < (q + 1) * 64; ++b) {
            unsigned c4 = histo_d[(size_t)b * HWORDS + w];
            histo_d[(size_t)b * HWORDS + w] = run;
            run += c4;  // byte-safe: deg < 256
        }
    }
    __syncthreads();
    int i = blockIdx.x * 256 + tid;
    int v = 0;
    if (i < n) {
        int sh = (tid & 3) * 8;
        v = (di4[tid >> 2] >> sh) & 255;
        int dgo = (do4[tid >> 2] >> sh) & 255;
        nd[i] = rsqrtf((float)max(v, 1));
        ns[i] = rsqrtf((float)max(dgo, 1));
    }
    int x = v;
#pragma unroll
    for (int off = 1; off < 64; off <<= 1) {
        int t = __shfl_up(x, off, 64);
        if (lane >= off) x += t;
    }
    __shared__ int ws[4];
    if (lane == 63) ws[q] = x;
    __syncthreads();
    int wo = 0;
    for (int k = 0; k < q; ++k) wo += ws[k];
    int incl = wo + x;
    if (i < n) rp[i] = incl - v;          // block-local exclusive
    if (tid == 255) bsum[blockIdx.x] = incl;
}

// scan of block sums
__global__ __launch_bounds__(512) void k_scan2(int* __restrict__ bsum, int nb,
                                               int* __restrict__ rpN) {
    __shared__ int s[512];
    const int tid = threadIdx.x;
    int v = (tid < nb) ? bsum[tid] : 0;
    s[tid] = v;
    __syncthreads();
    for (int off = 1; off < 512; off <<= 1) {
        int t = (tid >= off) ? s[tid - off] : 0;
        __syncthreads();
        s[tid] += t;
        __syncthreads();
    }
    if (tid < nb) bsum[tid] = s[tid] - v;  // exclusive block offsets
    if (tid == nb - 1) *rpN = v;           // last block's local total
}

// ---------------- scatter2: rank via LDS byte-atomic, place edges -----------------------
__global__ __launch_bounds__(256) void k_scatter2(const int* __restrict__ src,
                                                  const int* __restrict__ dst, int E,
                                                  const int* __restrict__ rp,
                                                  const int* __restrict__ bsum,
                                                  const unsigned* __restrict__ pfx_all,
                                                  int* __restrict__ csr) {
    __shared__ unsigned Hd[HWORDS];
    for (int i = threadIdx.x; i < HWORDS; i += 256) Hd[i] = 0;
    __syncthreads();
    const int c = blockIdx.x;
    const int perB = ((E + NHD - 1) / NHD + 3) & ~3;
    const int e0 = min(c * perB, E), e1 = min(e0 + perB, E);
    const unsigned* pfx = pfx_all + (size_t)c * HWORDS;
    int i = e0 + threadIdx.x * 4;
    for (; i + 3 < e1; i += 1024) {
        int4 d4 = *(const int4*)(dst + i);
        int4 s4 = *(const int4*)(src + i);
#define PROC(dd, ss)                                                            \
        {                                                                       \
            int sh = ((dd) & 3) * 8;                                            \
            int base = rp[dd] + bsum[(dd) >> 8] +                               \
                       (int)((pfx[(dd) >> 2] >> sh) & 255u);                    \
            unsigned old = atomicAdd(&Hd[(dd) >> 2], 1u << sh);                 \
            csr[base + (int)((old >> sh) & 255u)] = (ss);                       \
        }
        PROC(d4.x, s4.x) PROC(d4.y, s4.y) PROC(d4.z, s4.z) PROC(d4.w, s4.w)
    }
    for (; i < e1; ++i) PROC(dst[i], src[i])
#undef PROC
}

// ---------------- plain GEMM (layers 1,2; pre-transposed fp16 Wt) ----------------------
template <int BN, bool F32A>
__global__ __launch_bounds__(256) void k_gemm(const void* __restrict__ A,
                                              const __half* __restrict__ Wt,
                                              __half* __restrict__ C, int n) {
    __shared__ __half Al[128 * 136];
    __shared__ __half Bl[BN * 136];
    gemm_body<BN, F32A, false>(A, Wt, Al, Bl, C, n, blockIdx.x);
}

// ---------------- aggregation D=128: wave/node, half2/lane, masked 8-wide rounds ----
// SSCALE: fold ns[src] per edge (layer 0). Output fp16, pre-scaled by ns[node].
template <bool RELU, bool SSCALE>
__global__ __launch_bounds__(256) void k_agg128h(const __half2* __restrict__ H,  // [N][64]
                                                 const int* __restrict__ rp,
                                                 const int* __restrict__ bsum,
                                                 const int* __restrict__ cs,
                                                 const float* __restrict__ nd,
                                                 const float* __restrict__ ns,
                                                 const float* __restrict__ b,
                                                 __half2* __restrict__ out, int n) {
    const int wid = threadIdx.x >> 6, lane = threadIdx.x & 63;
    const int node = blockIdx.x * 4 + wid;
    if (node >= n) return;
    const int beg = rp[node] + bsum[node >> 8];
    const int end = rp[node + 1] + bsum[(node + 1) >> 8];
    float2 a0 = make_float2(0.f, 0.f), a1 = a0, a2 = a0, a3 = a0;
    float2 a4 = a0, a5 = a0, a6 = a0, a7 = a0;
    for (int e = beg; e < end; e += 8) {
        int s[8];
        float w[8];
#pragma unroll
        for (int j = 0; j < 8; ++j) {
            int idx = e + j;
            int r = (idx < end) ? idx : beg;                  // wave-uniform clamp
            r = __builtin_amdgcn_readfirstlane(r);            // scalarize csr index
            s[j] = cs[r];
            w[j] = (idx < end) ? 1.f : 0.f;
        }
        if (SSCALE) {
#pragma unroll
            for (int j = 0; j < 8; ++j) w[j] *= ns[s[j]];
        }
        float2 v0 = __half22float2(H[(size_t)s[0] * 64 + lane]);
        float2 v1 = __half22float2(H[(size_t)s[1] * 64 + lane]);
        float2 v2 = __half22float2(H[(size_t)s[2] * 64 + lane]);
        float2 v3 = __half22float2(H[(size_t)s[3] * 64 + lane]);
        float2 v4 = __half22float2(H[(size_t)s[4] * 64 + lane]);
        float2 v5 = __half22float2(H[(size_t)s[5] * 64 + lane]);
        float2 v6 = __half22float2(H[(size_t)s[6] * 64 + lane]);
        float2 v7 = __half22float2(H[(size_t)s[7] * 64 + lane]);
        a0.x = fmaf(v0.x, w[0], a0.x); a0.y = fmaf(v0.y, w[0], a0.y);
        a1.x = fmaf(v1.x, w[1], a1.x); a1.y = fmaf(v1.y, w[1], a1.y);
        a2.x = fmaf(v2.x, w[2], a2.x); a2.y = fmaf(v2.y, w[2], a2.y);
        a3.x = fmaf(v3.x, w[3], a3.x); a3.y = fmaf(v3.y, w[3], a3.y);
        a4.x = fmaf(v4.x, w[4], a4.x); a4.y = fmaf(v4.y, w[4], a4.y);
        a5.x = fmaf(v5.x, w[5], a5.x); a5.y = fmaf(v5.y, w[5], a5.y);
        a6.x = fmaf(v6.x, w[6], a6.x); a6.y = fmaf(v6.y, w[6], a6.y);
        a7.x = fmaf(v7.x, w[7], a7.x); a7.y = fmaf(v7.y, w[7], a7.y);
    }
    const float sc = nd[node];
    const float sn = ns[node];
    float2 bb = ((const float2*)b)[lane];
    float ax = ((a0.x + a1.x) + (a2.x + a3.x)) + ((a4.x + a5.x) + (a6.x + a7.x));
    float ay = ((a0.y + a1.y) + (a2.y + a3.y)) + ((a4.y + a5.y) + (a6.y + a7.y));
    float ox = ax * sc + bb.x;
    float oy = ay * sc + bb.y;
    if (RELU) { ox = fmaxf(ox, 0.f); oy = fmaxf(oy, 0.f); }
    ox *= sn; oy *= sn;
    out[(size_t)node * 64 + lane] = __floats2half2_rn(ox, oy);
}

// ---------------- aggregation D=64: wave/node, half/lane, masked 8-wide; f32 out --------
__global__ __launch_bounds__(256) void k_agg64h(const __half* __restrict__ H,  // [N][64]
                                                const int* __restrict__ rp,
                                                const int* __restrict__ bsum,
                                                const int* __restrict__ cs,
                                                const float* __restrict__ nd,
                                                const float* __restrict__ b,
                                                float* __restrict__ out, int n) {
    const int wid = threadIdx.x >> 6, lane = threadIdx.x & 63;
    const int node = blockIdx.x * 4 + wid;
    if (node >= n) return;
    const int beg = rp[node] + bsum[node >> 8];
    const int end = rp[node + 1] + bsum[(node + 1) >> 8];
    float a0 = 0.f, a1 = 0.f, a2 = 0.f, a3 = 0.f;
    float a4 = 0.f, a5 = 0.f, a6 = 0.f, a7 = 0.f;
    for (int e = beg; e < end; e += 8) {
        int s[8];
        float w[8];
#pragma unroll
        for (int j = 0; j < 8; ++j) {
            int idx = e + j;
            int r = (idx < end) ? idx : beg;
            r = __builtin_amdgcn_readfirstlane(r);
            s[j] = cs[r];
            w[j] = (idx < end) ? 1.f : 0.f;
        }
        a0 = fmaf(__half2float(H[(size_t)s[0] * 64 + lane]), w[0], a0);
        a1 = fmaf(__half2float(H[(size_t)s[1] * 64 + lane]), w[1], a1);
        a2 = fmaf(__half2float(H[(size_t)s[2] * 64 + lane]), w[2], a2);
        a3 = fmaf(__half2float(H[(size_t)s[3] * 64 + lane]), w[3], a3);
        a4 = fmaf(__half2float(H[(size_t)s[4] * 64 + lane]), w[4], a4);
        a5 = fmaf(__half2float(H[(size_t)s[5] * 64 + lane]), w[5], a5);
        a6 = fmaf(__half2float(H[(size_t)s[6] * 64 + lane]), w[6], a6);
        a7 = fmaf(__half2float(H[(size_t)s[7] * 64 + lane]), w[7], a7);
    }
    float a = ((a0 + a1) + (a2 + a3)) + ((a4 + a5) + (a6 + a7));
    out[(size_t)node * 64 + lane] = a * nd[node] + b[lane];
}

extern "C" void kernel_launch(void* const* d_in, const int* in_sizes, int n_in,
                              void* d_out, int out_size, void* d_ws, size_t ws_size,
                              hipStream_t stream) {
    const float* feat = (const float*)d_in[0];
    const int* ei = (const int*)d_in[1];
    const float* W0 = (const float*)d_in[2];
    const float* b0 = (const float*)d_in[3];
    const float* W1 = (const float*)d_in[4];
    const float* b1 = (const float*)d_in[5];
    const float* W2 = (const float*)d_in[6];
    const float* b2 = (const float*)d_in[7];
    float* out = (float*)d_out;

    const int N = in_sizes[0] / 128;  // 100000
    const int E = in_sizes[1] / 2;    // 1600000
    const int* src = ei;
    const int* dst = ei + E;
    const int NB = (N + 255) / 256;   // 391 scan blocks (= HWORDS/64)

    // workspace layout (16B-aligned chunks)
    char* w = (char*)d_ws;
    float* norm_src = (float*)w; w += (size_t)N * 4;
    float* norm_dst = (float*)w; w += (size_t)N * 4;
    unsigned* histo_s = (unsigned*)w; w += (size_t)NHS * HWORDS * 4;
    unsigned* histo_d = (unsigned*)w; w += (size_t)NHD * HWORDS * 4;
    int* rp    = (int*)w;        w += ((size_t)(N + 1) * 4 + 15) / 16 * 16;
    int* bsum  = (int*)w;        w += 512 * 4;
    int* csr   = (int*)w;        w += (size_t)E * 4;
    __half* Wt1 = (__half*)w;    w += 128 * 128 * 2;
    __half* Wt2 = (__half*)w;    w += 128 * 64 * 2;
    __half* Hb = (__half*)w;     w += (size_t)N * 128 * 2;  // GEMM out (gather src)
    __half* Xb = (__half*)w;     w += (size_t)N * 128 * 2;  // agg out / next GEMM in

    const int GB = (N + 127) / 128;   // 782 GEMM blocks
    const int agg_grid = (N + 3) / 4;

    // fused: GEMM0 (Hb = feat @ W0) || src/dst histograms || Wt1/Wt2 prep
    k_pre<<<GB + NHS + NHD + 2, 256, 0, stream>>>(feat, W0, Hb, N, GB,
                                                  src, dst, E, histo_s, histo_d,
                                                  W1, W2, Wt1, Wt2);
    k_scan1<<<NB, 256, 0, stream>>>(histo_s, histo_d, rp, bsum, norm_src, norm_dst, N);
    k_scan2<<<1, 512, 0, stream>>>(bsum, NB, rp + N);
    k_scatter2<<<NHD, 256, 0, stream>>>(src, dst, E, rp, bsum, histo_d, csr);

    // layer 0: gather Hb with per-edge ns[src]; out pre-scaled by ns
    k_agg128h<true, true><<<agg_grid, 256, 0, stream>>>((const __half2*)Hb, rp, bsum, csr,
                                                        norm_dst, norm_src, b0, (__half2*)Xb, N);
    // layer 1
    k_gemm<128, false><<<GB, 256, 0, stream>>>(Xb, Wt1, Hb, N);
    k_agg128h<true, false><<<agg_grid, 256, 0, stream>>>((const __half2*)Hb, rp, bsum, csr,
                                                         norm_dst, norm_src, b1, (__half2*)Xb, N);
    // layer 2 (BN=64, no relu, f32 out)
    k_gemm<64, false><<<GB, 256, 0, stream>>>(Xb, Wt2, Hb, N);
    k_agg64h<<<agg_grid, 256, 0, stream>>>(Hb, rp, bsum, csr, norm_dst, b2, out, N);
}

// Round 19
// 348.810 us; speedup vs baseline: 1.8892x; 1.0251x over previous
//
#include <hip/hip_runtime.h>
#include <hip/hip_fp16.h>

// GCN 3-layer: fp16 intermediates, f32 accum, MFMA GEMMs, zero-global-atomic CSR.
// Round-16 structure + 1024-thread histogram/scatter blocks (16 waves vs 4 on the
// 100KB-LDS 1-block/CU kernels), NHS=64, 4-way parallel scan1.
// Agg: wave/node, uniform masked 8-wide rounds, scalarized csr index loads.
// Math: (x*ns)@W == (x@W)*ns_row; layer-0 folds ns[src] into the gather (fma),
// later layers pre-scale the agg output by ns (relu(x)*s == relu(x*s), s>0).

typedef _Float16 h8 __attribute__((ext_vector_type(8)));
typedef float f32x4 __attribute__((ext_vector_type(4)));

#define HWORDS 25024   // ceil(100000/4), = 391*64 exactly
#define NHS 64         // src histogram chunks (4 per scan1 wave)
#define NHD 256        // dst histogram chunks

// ---------------- pre: {64 src hist} | {256 dst hist} | {Wt0/Wt1/Wt2 prep} -------------
__global__ __launch_bounds__(1024) void k_pre(const int* __restrict__ src,
                                              const int* __restrict__ dst, int E,
                                              unsigned* __restrict__ histo_s,
                                              unsigned* __restrict__ histo_d,
                                              const float* __restrict__ W0,
                                              const float* __restrict__ W1,
                                              const float* __restrict__ W2,
                                              __half* __restrict__ Wt0,
                                              __half* __restrict__ Wt1,
                                              __half* __restrict__ Wt2) {
    __shared__ unsigned H[HWORDS];
    const int b = blockIdx.x;
    const int tid = threadIdx.x;
    if (b < NHS + NHD) {
        const bool isS = b < NHS;
        const int c = isS ? b : b - NHS;
        const int NC = isS ? NHS : NHD;
        const int* arr = isS ? src : dst;
        unsigned* outp = (isS ? histo_s : histo_d) + (size_t)c * HWORDS;
        for (int i = tid; i < HWORDS; i += 1024) H[i] = 0;
        __syncthreads();
        const int perB = ((E + NC - 1) / NC + 3) & ~3;
        const int e0 = min(c * perB, E), e1 = min(e0 + perB, E);
        int i = e0 + tid * 4;
        for (; i + 3 < e1; i += 4096) {
            int4 s4 = *(const int4*)(arr + i);
            atomicAdd(&H[s4.x >> 2], 1u << ((s4.x & 3) * 8));
            atomicAdd(&H[s4.y >> 2], 1u << ((s4.y & 3) * 8));
            atomicAdd(&H[s4.z >> 2], 1u << ((s4.z & 3) * 8));
            atomicAdd(&H[s4.w >> 2], 1u << ((s4.w & 3) * 8));
        }
        for (; i < e1; ++i) {
            int s = arr[i];
            atomicAdd(&H[s >> 2], 1u << ((s & 3) * 8));
        }
        __syncthreads();
        for (int i2 = tid; i2 < HWORDS; i2 += 1024) outp[i2] = H[i2];
    } else {
        // Wt prep: Wt[n][k] = (half)W[k][n]; 40960 elements
        for (int j = tid; j < 40960; j += 1024) {
            if (j < 16384) {
                int nn = j >> 7, k = j & 127;
                Wt0[j] = __float2half(W0[k * 128 + nn]);
            } else if (j < 32768) {
                int i2 = j - 16384;
                int nn = i2 >> 7, k = i2 & 127;
                Wt1[i2] = __float2half(W1[k * 128 + nn]);
            } else {
                int i2 = j - 32768;
                int nn = i2 >> 7, k = i2 & 127;
                Wt2[i2] = __float2half(W2[k * 64 + nn]);
            }
        }
    }
}

// ---------------- scan1: 4-way parallel dst-prefix transform + norms + block scan ------
__global__ __launch_bounds__(256) void k_scan1(const unsigned* __restrict__ histo_s,
                                               unsigned* __restrict__ histo_d,
                                               int* __restrict__ rp,
                                               int* __restrict__ bsum,
                                               float* __restrict__ ns,
                                               float* __restrict__ nd, int n) {
    __shared__ unsigned qsd[4][64];  // quarter sums (dst), packed bytes
    __shared__ unsigned qss[4][64];  // quarter sums (src)
    __shared__ unsigned di4[64];     // packed deg_i for this block's 256 nodes
    __shared__ unsigned do4[64];     // packed deg_o
    const int tid = threadIdx.x, lane = tid & 63, q = tid >> 6;
    const int w = blockIdx.x * 64 + lane;  // word index (4 nodes); 391*64 == HWORDS
    {
        unsigned s = 0;
#pragma unroll 8
        for (int b = q * (NHD / 4); b < (q + 1) * (NHD / 4); ++b)
            s += histo_d[(size_t)b * HWORDS + w];
        qsd[q][lane] = s;
        unsigned s2 = 0;
#pragma unroll
        for (int b = q * (NHS / 4); b < (q + 1) * (NHS / 4); ++b)
            s2 += histo_s[(size_t)b * HWORDS + w];
        qss[q][lane] = s2;
    }
    __syncthreads();
    if (q == 0) {
        di4[lane] = qsd[0][lane] + qsd[1][lane] + qsd[2][lane] + qsd[3][lane];
        do4[lane] = qss[0][lane] + qss[1][lane] + qss[2][lane] + qss[3][lane];
    }
    // pass 2: write exclusive chunk prefixes with quarter base
    {
        unsigned run = 0;
        for (int k = 0; k < q; ++k) run += qsd[k][lane];
#pragma unroll 8
        for (int b = q * (NHD / 4); b < (q + 1) * (NHD / 4); ++b) {
            unsigned c4 = histo_d[(size_t)b * HWORDS + w];
            histo_d[(size_t)b * HWORDS + w] = run;
            run += c4;  // byte-safe: deg < 256
        }
    }
    __syncthreads();
    int i = blockIdx.x * 256 + tid;
    int v = 0;
    if (i < n) {
        int sh = (tid & 3) * 8;
        v = (di4[tid >> 2] >> sh) & 255;
        int dgo = (do4[tid >> 2] >> sh) & 255;
        nd[i] = rsqrtf((float)max(v, 1));
        ns[i] = rsqrtf((float)max(dgo, 1));
    }
    int x = v;
#pragma unroll
    for (int off = 1; off < 64; off <<= 1) {
        int t = __shfl_up(x, off, 64);
        if (lane >= off) x += t;
    }
    __shared__ int ws[4];
    if (lane == 63) ws[q] = x;
    __syncthreads();
    int wo = 0;
    for (int k = 0; k < q; ++k) wo += ws[k];
    int incl = wo + x;
    if (i < n) rp[i] = incl - v;          // block-local exclusive
    if (tid == 255) bsum[blockIdx.x] = incl;
}

// scan of block sums
__global__ __launch_bounds__(512) void k_scan2(int* __restrict__ bsum, int nb,
                                               int* __restrict__ rpN) {
    __shared__ int s[512];
    const int tid = threadIdx.x;
    int v = (tid < nb) ? bsum[tid] : 0;
    s[tid] = v;
    __syncthreads();
    for (int off = 1; off < 512; off <<= 1) {
        int t = (tid >= off) ? s[tid - off] : 0;
        __syncthreads();
        s[tid] += t;
        __syncthreads();
    }
    if (tid < nb) bsum[tid] = s[tid] - v;  // exclusive block offsets
    if (tid == nb - 1) *rpN = v;           // last block's local total
}

// ---------------- scatter2: rank via LDS byte-atomic, place edges (1024 threads) -------
__global__ __launch_bounds__(1024) void k_scatter2(const int* __restrict__ src,
                                                   const int* __restrict__ dst, int E,
                                                   const int* __restrict__ rp,
                                                   const int* __restrict__ bsum,
                                                   const unsigned* __restrict__ pfx_all,
                                                   int* __restrict__ csr) {
    __shared__ unsigned Hd[HWORDS];
    const int tid = threadIdx.x;
    for (int i = tid; i < HWORDS; i += 1024) Hd[i] = 0;
    __syncthreads();
    const int c = blockIdx.x;
    const int perB = ((E + NHD - 1) / NHD + 3) & ~3;
    const int e0 = min(c * perB, E), e1 = min(e0 + perB, E);
    const unsigned* pfx = pfx_all + (size_t)c * HWORDS;
    int i = e0 + tid * 4;
    for (; i + 3 < e1; i += 4096) {
        int4 d4 = *(const int4*)(dst + i);
        int4 s4 = *(const int4*)(src + i);
#define PROC(dd, ss)                                                            \
        {                                                                       \
            int sh = ((dd) & 3) * 8;                                            \
            int base = rp[dd] + bsum[(dd) >> 8] +                               \
                       (int)((pfx[(dd) >> 2] >> sh) & 255u);                    \
            unsigned old = atomicAdd(&Hd[(dd) >> 2], 1u << sh);                 \
            csr[base + (int)((old >> sh) & 255u)] = (ss);                       \
        }
        PROC(d4.x, s4.x) PROC(d4.y, s4.y) PROC(d4.z, s4.z) PROC(d4.w, s4.w)
    }
    for (; i < e1; ++i) PROC(dst[i], src[i])
#undef PROC
}

// ---------------- shared GEMM body: C[n,BN](fp16) = A[n,128] @ Wt[BN,128]^T ----------------
// v_mfma_f32_16x16x32_f16; A/B frag = 8 halves at k=8*(lane>>4), row/col=lane&15;
// C/D: col=lane&15, row=(lane>>4)*4+reg (guide m89-verified; round-6 validated).
template <int BN, bool F32A>
__device__ __forceinline__ void gemm_body(const void* __restrict__ Ap,
                                          const __half* __restrict__ Wt,
                                          __half* __restrict__ C, int n, int gb) {
    constexpr int K = 128, BM = 128, LDR = K + 8;  // halves; 272B rows
    __shared__ __half Al[BM * LDR];
    __shared__ __half Bl[BN * LDR];
    const int tid = threadIdx.x;
    const int row0 = gb * BM;
    if (F32A) {
        const float* A = (const float*)Ap;
#pragma unroll
        for (int q = 0; q < 16; ++q) {
            int fi = q * 256 + tid;
            int r = fi >> 5, c = (fi & 31) * 4;
            int gr = row0 + r;
            float4 v = make_float4(0.f, 0.f, 0.f, 0.f);
            if (gr < n) v = *(const float4*)(A + (size_t)gr * K + c);
            __half2 h0 = __floats2half2_rn(v.x, v.y);
            __half2 h1 = __floats2half2_rn(v.z, v.w);
            uint2 pk = make_uint2(*(unsigned*)&h0, *(unsigned*)&h1);
            *(uint2*)&Al[r * LDR + c] = pk;
        }
    } else {
        const __half* A = (const __half*)Ap;
#pragma unroll
        for (int q = 0; q < 8; ++q) {
            int fi = q * 256 + tid;
            int r = fi >> 4, c = (fi & 15) * 8;
            int gr = row0 + r;
            float4 v = make_float4(0.f, 0.f, 0.f, 0.f);
            if (gr < n) v = *(const float4*)(A + (size_t)gr * K + c);
            *(float4*)&Al[r * LDR + c] = v;
        }
    }
#pragma unroll
    for (int q = 0; q < BN / 16; ++q) {
        int fi = q * 256 + tid;
        int r = fi >> 4, c = (fi & 15) * 8;
        *(float4*)&Bl[r * LDR + c] = *(const float4*)(Wt + (size_t)r * K + c);
    }
    __syncthreads();
    const int wid = tid >> 6, lane = tid & 63;
    const int lo = lane & 15, hi = lane >> 4;
    constexpr int NC = BN / 16;
    f32x4 acc[2][NC];
#pragma unroll
    for (int t = 0; t < 2; ++t)
#pragma unroll
        for (int c = 0; c < NC; ++c) acc[t][c] = (f32x4){0.f, 0.f, 0.f, 0.f};
#pragma unroll
    for (int kc = 0; kc < 4; ++kc) {
        h8 aF[2];
#pragma unroll
        for (int t = 0; t < 2; ++t)
            aF[t] = *(const h8*)&Al[(32 * wid + 16 * t + lo) * LDR + 32 * kc + 8 * hi];
#pragma unroll
        for (int c = 0; c < NC; ++c) {
            h8 bF = *(const h8*)&Bl[(16 * c + lo) * LDR + 32 * kc + 8 * hi];
#pragma unroll
            for (int t = 0; t < 2; ++t)
                acc[t][c] = __builtin_amdgcn_mfma_f32_16x16x32_f16(aF[t], bF, acc[t][c], 0, 0, 0);
        }
    }
#pragma unroll
    for (int t = 0; t < 2; ++t) {
#pragma unroll
        for (int j = 0; j < 4; ++j) {
            int gr = row0 + 32 * wid + 16 * t + 4 * hi + j;
            if (gr < n) {
#pragma unroll
                for (int c = 0; c < NC; ++c)
                    C[(size_t)gr * BN + 16 * c + lo] = __float2half(acc[t][c][j]);
            }
        }
    }
}

template <int BN, bool F32A>
__global__ __launch_bounds__(256) void k_gemm(const void* __restrict__ A,
                                              const __half* __restrict__ Wt,
                                              __half* __restrict__ C, int n) {
    gemm_body<BN, F32A>(A, Wt, C, n, blockIdx.x);
}

// ---------------- aggregation D=128: wave/node, half2/lane, masked 8-wide rounds ----
// SSCALE: fold ns[src] per edge (layer 0). Output fp16, pre-scaled by ns[node].
template <bool RELU, bool SSCALE>
__global__ __launch_bounds__(256) void k_agg128h(const __half2* __restrict__ H,  // [N][64]
                                                 const int* __restrict__ rp,
                                                 const int* __restrict__ bsum,
                                                 const int* __restrict__ cs,
                                                 const float* __restrict__ nd,
                                                 const float* __restrict__ ns,
                                                 const float* __restrict__ b,
                                                 __half2* __restrict__ out, int n) {
    const int wid = threadIdx.x >> 6, lane = threadIdx.x & 63;
    const int node = blockIdx.x * 4 + wid;
    if (node >= n) return;
    const int beg = rp[node] + bsum[node >> 8];
    const int end = rp[node + 1] + bsum[(node + 1) >> 8];
    float2 a0 = make_float2(0.f, 0.f), a1 = a0, a2 = a0, a3 = a0;
    float2 a4 = a0, a5 = a0, a6 = a0, a7 = a0;
    for (int e = beg; e < end; e += 8) {
        int s[8];
        float w[8];
#pragma unroll
        for (int j = 0; j < 8; ++j) {
            int idx = e + j;
            int r = (idx < end) ? idx : beg;                  // wave-uniform clamp
            r = __builtin_amdgcn_readfirstlane(r);            // scalarize csr index
            s[j] = cs[r];
            w[j] = (idx < end) ? 1.f : 0.f;
        }
        if (SSCALE) {
#pragma unroll
            for (int j = 0; j < 8; ++j) w[j] *= ns[s[j]];
        }
        float2 v0 = __half22float2(H[(size_t)s[0] * 64 + lane]);
        float2 v1 = __half22float2(H[(size_t)s[1] * 64 + lane]);
        float2 v2 = __half22float2(H[(size_t)s[2] * 64 + lane]);
        float2 v3 = __half22float2(H[(size_t)s[3] * 64 + lane]);
        float2 v4 = __half22float2(H[(size_t)s[4] * 64 + lane]);
        float2 v5 = __half22float2(H[(size_t)s[5] * 64 + lane]);
        float2 v6 = __half22float2(H[(size_t)s[6] * 64 + lane]);
        float2 v7 = __half22float2(H[(size_t)s[7] * 64 + lane]);
        a0.x = fmaf(v0.x, w[0], a0.x); a0.y = fmaf(v0.y, w[0], a0.y);
        a1.x = fmaf(v1.x, w[1], a1.x); a1.y = fmaf(v1.y, w[1], a1.y);
        a2.x = fmaf(v2.x, w[2], a2.x); a2.y = fmaf(v2.y, w[2], a2.y);
        a3.x = fmaf(v3.x, w[3], a3.x); a3.y = fmaf(v3.y, w[3], a3.y);
        a4.x = fmaf(v4.x, w[4], a4.x); a4.y = fmaf(v4.y, w[4], a4.y);
        a5.x = fmaf(v5.x, w[5], a5.x); a5.y = fmaf(v5.y, w[5], a5.y);
        a6.x = fmaf(v6.x, w[6], a6.x); a6.y = fmaf(v6.y, w[6], a6.y);
        a7.x = fmaf(v7.x, w[7], a7.x); a7.y = fmaf(v7.y, w[7], a7.y);
    }
    const float sc = nd[node];
    const float sn = ns[node];
    float2 bb = ((const float2*)b)[lane];
    float ax = ((a0.x + a1.x) + (a2.x + a3.x)) + ((a4.x + a5.x) + (a6.x + a7.x));
    float ay = ((a0.y + a1.y) + (a2.y + a3.y)) + ((a4.y + a5.y) + (a6.y + a7.y));
    float ox = ax * sc + bb.x;
    float oy = ay * sc + bb.y;
    if (RELU) { ox = fmaxf(ox, 0.f); oy = fmaxf(oy, 0.f); }
    ox *= sn; oy *= sn;
    out[(size_t)node * 64 + lane] = __floats2half2_rn(ox, oy);
}

// ---------------- aggregation D=64: wave/node, half/lane, masked 8-wide; f32 out --------
__global__ __launch_bounds__(256) void k_agg64h(const __half* __restrict__ H,  // [N][64]
                                                const int* __restrict__ rp,
                                                const int* __restrict__ bsum,
                                                const int* __restrict__ cs,
                                                const float* __restrict__ nd,
                                                const float* __restrict__ b,
                                                float* __restrict__ out, int n) {
    const int wid = threadIdx.x >> 6, lane = threadIdx.x & 63;
    const int node = blockIdx.x * 4 + wid;
    if (node >= n) return;
    const int beg = rp[node] + bsum[node >> 8];
    const int end = rp[node + 1] + bsum[(node + 1) >> 8];
    float a0 = 0.f, a1 = 0.f, a2 = 0.f, a3 = 0.f;
    float a4 = 0.f, a5 = 0.f, a6 = 0.f, a7 = 0.f;
    for (int e = beg; e < end; e += 8) {
        int s[8];
        float w[8];
#pragma unroll
        for (int j = 0; j < 8; ++j) {
            int idx = e + j;
            int r = (idx < end) ? idx : beg;
            r = __builtin_amdgcn_readfirstlane(r);
            s[j] = cs[r];
            w[j] = (idx < end) ? 1.f : 0.f;
        }
        a0 = fmaf(__half2float(H[(size_t)s[0] * 64 + lane]), w[0], a0);
        a1 = fmaf(__half2float(H[(size_t)s[1] * 64 + lane]), w[1], a1);
        a2 = fmaf(__half2float(H[(size_t)s[2] * 64 + lane]), w[2], a2);
        a3 = fmaf(__half2float(H[(size_t)s[3] * 64 + lane]), w[3], a3);
        a4 = fmaf(__half2float(H[(size_t)s[4] * 64 + lane]), w[4], a4);
        a5 = fmaf(__half2float(H[(size_t)s[5] * 64 + lane]), w[5], a5);
        a6 = fmaf(__half2float(H[(size_t)s[6] * 64 + lane]), w[6], a6);
        a7 = fmaf(__half2float(H[(size_t)s[7] * 64 + lane]), w[7], a7);
    }
    float a = ((a0 + a1) + (a2 + a3)) + ((a4 + a5) + (a6 + a7));
    out[(size_t)node * 64 + lane] = a * nd[node] + b[lane];
}

extern "C" void kernel_launch(void* const* d_in, const int* in_sizes, int n_in,
                              void* d_out, int out_size, void* d_ws, size_t ws_size,
                              hipStream_t stream) {
    const float* feat = (const float*)d_in[0];
    const int* ei = (const int*)d_in[1];
    const float* W0 = (const float*)d_in[2];
    const float* b0 = (const float*)d_in[3];
    const float* W1 = (const float*)d_in[4];
    const float* b1 = (const float*)d_in[5];
    const float* W2 = (const float*)d_in[6];
    const float* b2 = (const float*)d_in[7];
    float* out = (float*)d_out;

    const int N = in_sizes[0] / 128;  // 100000
    const int E = in_sizes[1] / 2;    // 1600000
    const int* src = ei;
    const int* dst = ei + E;
    const int NB = (N + 255) / 256;   // 391 scan blocks (= HWORDS/64)

    // workspace layout (16B-aligned chunks)
    char* w = (char*)d_ws;
    float* norm_src = (float*)w; w += (size_t)N * 4;
    float* norm_dst = (float*)w; w += (size_t)N * 4;
    unsigned* histo_s = (unsigned*)w; w += (size_t)NHS * HWORDS * 4;
    unsigned* histo_d = (unsigned*)w; w += (size_t)NHD * HWORDS * 4;
    int* rp    = (int*)w;        w += ((size_t)(N + 1) * 4 + 15) / 16 * 16;
    int* bsum  = (int*)w;        w += 512 * 4;
    int* csr   = (int*)w;        w += (size_t)E * 4;
    __half* Wt0 = (__half*)w;    w += 128 * 128 * 2;
    __half* Wt1 = (__half*)w;    w += 128 * 128 * 2;
    __half* Wt2 = (__half*)w;    w += 128 * 64 * 2;
    __half* Hb = (__half*)w;     w += (size_t)N * 128 * 2;  // GEMM out (gather src)
    __half* Xb = (__half*)w;     w += (size_t)N * 128 * 2;  // agg out / next GEMM in

    const int GB = (N + 127) / 128;   // 782 GEMM blocks
    const int agg_grid = (N + 3) / 4;

    // CSR build, no global atomics (1024-thread blocks for LDS-heavy kernels)
    k_pre<<<NHS + NHD + 1, 1024, 0, stream>>>(src, dst, E, histo_s, histo_d,
                                              W0, W1, W2, Wt0, Wt1, Wt2);
    k_scan1<<<NB, 256, 0, stream>>>(histo_s, histo_d, rp, bsum, norm_src, norm_dst, N);
    k_scan2<<<1, 512, 0, stream>>>(bsum, NB, rp + N);
    k_scatter2<<<NHD, 1024, 0, stream>>>(src, dst, E, rp, bsum, histo_d, csr);

    // layer 0
    k_gemm<128, true><<<GB, 256, 0, stream>>>(feat, Wt0, Hb, N);
    k_agg128h<true, true><<<agg_grid, 256, 0, stream>>>((const __half2*)Hb, rp, bsum, csr,
                                                        norm_dst, norm_src, b0, (__half2*)Xb, N);
    // layer 1
    k_gemm<128, false><<<GB, 256, 0, stream>>>(Xb, Wt1, Hb, N);
    k_agg128h<true, false><<<agg_grid, 256, 0, stream>>>((const __half2*)Hb, rp, bsum, csr,
                                                         norm_dst, norm_src, b1, (__half2*)Xb, N);
    // layer 2 (BN=64, no relu, f32 out)
    k_gemm<64, false><<<GB, 256, 0, stream>>>(Xb, Wt2, Hb, N);
    k_agg64h<<<agg_grid, 256, 0, stream>>>(Hb, rp, bsum, csr, norm_dst, b2, out, N);
}

// Round 20
// 346.414 us; speedup vs baseline: 1.9023x; 1.0069x over previous
//
#include <hip/hip_runtime.h>
#include <hip/hip_fp16.h>

// GCN 3-layer: fp16 intermediates, f32 accum, MFMA GEMMs, zero-global-atomic CSR.
// Round-19 structure + rank capture in k_pre (LDS atomic returns old count ->
// pos[i] u8) + LDS-free streaming scatter fused with GEMM0 (block-partitioned).
// Agg: wave/node, uniform masked 8-wide rounds, scalarized csr index loads.
// Math: (x*ns)@W == (x@W)*ns_row; layer-0 folds ns[src] into the gather (fma),
// later layers pre-scale the agg output by ns (relu(x)*s == relu(x*s), s>0).

typedef _Float16 h8 __attribute__((ext_vector_type(8)));
typedef float f32x4 __attribute__((ext_vector_type(4)));

#define HWORDS 25024   // ceil(100000/4), = 391*64 exactly
#define NHS 64         // src histogram chunks
#define NHD 256        // dst histogram chunks

// ---------------- pre: {64 src hist} | {256 dst hist + pos} | {Wt prep} ----------------
__global__ __launch_bounds__(1024) void k_pre(const int* __restrict__ src,
                                              const int* __restrict__ dst, int E,
                                              unsigned* __restrict__ histo_s,
                                              unsigned* __restrict__ histo_d,
                                              unsigned char* __restrict__ pos,
                                              const float* __restrict__ W0,
                                              const float* __restrict__ W1,
                                              const float* __restrict__ W2,
                                              __half* __restrict__ Wt0,
                                              __half* __restrict__ Wt1,
                                              __half* __restrict__ Wt2) {
    __shared__ unsigned H[HWORDS];
    const int b = blockIdx.x;
    const int tid = threadIdx.x;
    if (b < NHS) {
        // src histogram (no pos)
        const int c = b;
        unsigned* outp = histo_s + (size_t)c * HWORDS;
        for (int i = tid; i < HWORDS; i += 1024) H[i] = 0;
        __syncthreads();
        const int perB = ((E + NHS - 1) / NHS + 3) & ~3;
        const int e0 = min(c * perB, E), e1 = min(e0 + perB, E);
        int i = e0 + tid * 4;
        for (; i + 3 < e1; i += 4096) {
            int4 s4 = *(const int4*)(src + i);
            atomicAdd(&H[s4.x >> 2], 1u << ((s4.x & 3) * 8));
            atomicAdd(&H[s4.y >> 2], 1u << ((s4.y & 3) * 8));
            atomicAdd(&H[s4.z >> 2], 1u << ((s4.z & 3) * 8));
            atomicAdd(&H[s4.w >> 2], 1u << ((s4.w & 3) * 8));
        }
        for (; i < e1; ++i) {
            int s = src[i];
            atomicAdd(&H[s >> 2], 1u << ((s & 3) * 8));
        }
        __syncthreads();
        for (int i2 = tid; i2 < HWORDS; i2 += 1024) outp[i2] = H[i2];
    } else if (b < NHS + NHD) {
        // dst histogram + per-edge rank capture
        const int c = b - NHS;
        unsigned* outp = histo_d + (size_t)c * HWORDS;
        for (int i = tid; i < HWORDS; i += 1024) H[i] = 0;
        __syncthreads();
        const int perB = ((E + NHD - 1) / NHD + 3) & ~3;
        const int e0 = min(c * perB, E), e1 = min(e0 + perB, E);
        int i = e0 + tid * 4;
        for (; i + 3 < e1; i += 4096) {
            int4 d4 = *(const int4*)(dst + i);
            unsigned o0 = atomicAdd(&H[d4.x >> 2], 1u << ((d4.x & 3) * 8));
            unsigned o1 = atomicAdd(&H[d4.y >> 2], 1u << ((d4.y & 3) * 8));
            unsigned o2 = atomicAdd(&H[d4.z >> 2], 1u << ((d4.z & 3) * 8));
            unsigned o3 = atomicAdd(&H[d4.w >> 2], 1u << ((d4.w & 3) * 8));
            uchar4 p4;
            p4.x = (unsigned char)((o0 >> ((d4.x & 3) * 8)) & 255u);
            p4.y = (unsigned char)((o1 >> ((d4.y & 3) * 8)) & 255u);
            p4.z = (unsigned char)((o2 >> ((d4.z & 3) * 8)) & 255u);
            p4.w = (unsigned char)((o3 >> ((d4.w & 3) * 8)) & 255u);
            *(uchar4*)(pos + i) = p4;
        }
        for (; i < e1; ++i) {
            int d = dst[i];
            unsigned o = atomicAdd(&H[d >> 2], 1u << ((d & 3) * 8));
            pos[i] = (unsigned char)((o >> ((d & 3) * 8)) & 255u);
        }
        __syncthreads();
        for (int i2 = tid; i2 < HWORDS; i2 += 1024) outp[i2] = H[i2];
    } else {
        // Wt prep: Wt[n][k] = (half)W[k][n]; 40960 elements
        for (int j = tid; j < 40960; j += 1024) {
            if (j < 16384) {
                int nn = j >> 7, k = j & 127;
                Wt0[j] = __float2half(W0[k * 128 + nn]);
            } else if (j < 32768) {
                int i2 = j - 16384;
                int nn = i2 >> 7, k = i2 & 127;
                Wt1[i2] = __float2half(W1[k * 128 + nn]);
            } else {
                int i2 = j - 32768;
                int nn = i2 >> 7, k = i2 & 127;
                Wt2[i2] = __float2half(W2[k * 64 + nn]);
            }
        }
    }
}

// ---------------- scan1: 4-way parallel dst-prefix transform + norms + block scan ------
__global__ __launch_bounds__(256) void k_scan1(const unsigned* __restrict__ histo_s,
                                               unsigned* __restrict__ histo_d,
                                               int* __restrict__ rp,
                                               int* __restrict__ bsum,
                                               float* __restrict__ ns,
                                               float* __restrict__ nd, int n) {
    __shared__ unsigned qsd[4][64];  // quarter sums (dst), packed bytes
    __shared__ unsigned qss[4][64];  // quarter sums (src)
    __shared__ unsigned di4[64];     // packed deg_i for this block's 256 nodes
    __shared__ unsigned do4[64];     // packed deg_o
    const int tid = threadIdx.x, lane = tid & 63, q = tid >> 6;
    const int w = blockIdx.x * 64 + lane;  // word index (4 nodes); 391*64 == HWORDS
    {
        unsigned s = 0;
#pragma unroll 8
        for (int b = q * (NHD / 4); b < (q + 1) * (NHD / 4); ++b)
            s += histo_d[(size_t)b * HWORDS + w];
        qsd[q][lane] = s;
        unsigned s2 = 0;
#pragma unroll
        for (int b = q * (NHS / 4); b < (q + 1) * (NHS / 4); ++b)
            s2 += histo_s[(size_t)b * HWORDS + w];
        qss[q][lane] = s2;
    }
    __syncthreads();
    if (q == 0) {
        di4[lane] = qsd[0][lane] + qsd[1][lane] + qsd[2][lane] + qsd[3][lane];
        do4[lane] = qss[0][lane] + qss[1][lane] + qss[2][lane] + qss[3][lane];
    }
    // pass 2: write exclusive chunk prefixes with quarter base
    {
        unsigned run = 0;
        for (int k = 0; k < q; ++k) run += qsd[k][lane];
#pragma unroll 8
        for (int b = q * (NHD / 4); b < (q + 1) * (NHD / 4); ++b) {
            unsigned c4 = histo_d[(size_t)b * HWORDS + w];
            histo_d[(size_t)b * HWORDS + w] = run;
            run += c4;  // byte-safe: deg < 256
        }
    }
    __syncthreads();
    int i = blockIdx.x * 256 + tid;
    int v = 0;
    if (i < n) {
        int sh = (tid & 3) * 8;
        v = (di4[tid >> 2] >> sh) & 255;
        int dgo = (do4[tid >> 2] >> sh) & 255;
        nd[i] = rsqrtf((float)max(v, 1));
        ns[i] = rsqrtf((float)max(dgo, 1));
    }
    int x = v;
#pragma unroll
    for (int off = 1; off < 64; off <<= 1) {
        int t = __shfl_up(x, off, 64);
        if (lane >= off) x += t;
    }
    __shared__ int ws[4];
    if (lane == 63) ws[q] = x;
    __syncthreads();
    int wo = 0;
    for (int k = 0; k < q; ++k) wo += ws[k];
    int incl = wo + x;
    if (i < n) rp[i] = incl - v;          // block-local exclusive
    if (tid == 255) bsum[blockIdx.x] = incl;
}

// scan of block sums
__global__ __launch_bounds__(512) void k_scan2(int* __restrict__ bsum, int nb,
                                               int* __restrict__ rpN) {
    __shared__ int s[512];
    const int tid = threadIdx.x;
    int v = (tid < nb) ? bsum[tid] : 0;
    s[tid] = v;
    __syncthreads();
    for (int off = 1; off < 512; off <<= 1) {
        int t = (tid >= off) ? s[tid - off] : 0;
        __syncthreads();
        s[tid] += t;
        __syncthreads();
    }
    if (tid < nb) bsum[tid] = s[tid] - v;  // exclusive block offsets
    if (tid == nb - 1) *rpN = v;           // last block's local total
}

// ---------------- shared GEMM body: C[n,BN](fp16) = A[n,128] @ Wt[BN,128]^T ----------------
// v_mfma_f32_16x16x32_f16; A/B frag = 8 halves at k=8*(lane>>4), row/col=lane&15;
// C/D: col=lane&15, row=(lane>>4)*4+reg (guide m89-verified; round-6 validated).
template <int BN, bool F32A>
__device__ __forceinline__ void gemm_body(const void* __restrict__ Ap,
                                          const __half* __restrict__ Wt,
                                          __half* __restrict__ C, int n, int gb) {
    constexpr int K = 128, BM = 128, LDR = K + 8;  // halves; 272B rows
    __shared__ __half Al[BM * LDR];
    __shared__ __half Bl[BN * LDR];
    const int tid = threadIdx.x;
    const int row0 = gb * BM;
    if (F32A) {
        const float* A = (const float*)Ap;
#pragma unroll
        for (int q = 0; q < 16; ++q) {
            int fi = q * 256 + tid;
            int r = fi >> 5, c = (fi & 31) * 4;
            int gr = row0 + r;
            float4 v = make_float4(0.f, 0.f, 0.f, 0.f);
            if (gr < n) v = *(const float4*)(A + (size_t)gr * K + c);
            __half2 h0 = __floats2half2_rn(v.x, v.y);
            __half2 h1 = __floats2half2_rn(v.z, v.w);
            uint2 pk = make_uint2(*(unsigned*)&h0, *(unsigned*)&h1);
            *(uint2*)&Al[r * LDR + c] = pk;
        }
    } else {
        const __half* A = (const __half*)Ap;
#pragma unroll
        for (int q = 0; q < 8; ++q) {
            int fi = q * 256 + tid;
            int r = fi >> 4, c = (fi & 15) * 8;
            int gr = row0 + r;
            float4 v = make_float4(0.f, 0.f, 0.f, 0.f);
            if (gr < n) v = *(const float4*)(A + (size_t)gr * K + c);
            *(float4*)&Al[r * LDR + c] = v;
        }
    }
#pragma unroll
    for (int q = 0; q < BN / 16; ++q) {
        int fi = q * 256 + tid;
        int r = fi >> 4, c = (fi & 15) * 8;
        *(float4*)&Bl[r * LDR + c] = *(const float4*)(Wt + (size_t)r * K + c);
    }
    __syncthreads();
    const int wid = tid >> 6, lane = tid & 63;
    const int lo = lane & 15, hi = lane >> 4;
    constexpr int NC = BN / 16;
    f32x4 acc[2][NC];
#pragma unroll
    for (int t = 0; t < 2; ++t)
#pragma unroll
        for (int c = 0; c < NC; ++c) acc[t][c] = (f32x4){0.f, 0.f, 0.f, 0.f};
#pragma unroll
    for (int kc = 0; kc < 4; ++kc) {
        h8 aF[2];
#pragma unroll
        for (int t = 0; t < 2; ++t)
            aF[t] = *(const h8*)&Al[(32 * wid + 16 * t + lo) * LDR + 32 * kc + 8 * hi];
#pragma unroll
        for (int c = 0; c < NC; ++c) {
            h8 bF = *(const h8*)&Bl[(16 * c + lo) * LDR + 32 * kc + 8 * hi];
#pragma unroll
            for (int t = 0; t < 2; ++t)
                acc[t][c] = __builtin_amdgcn_mfma_f32_16x16x32_f16(aF[t], bF, acc[t][c], 0, 0, 0);
        }
    }
#pragma unroll
    for (int t = 0; t < 2; ++t) {
#pragma unroll
        for (int j = 0; j < 4; ++j) {
            int gr = row0 + 32 * wid + 16 * t + 4 * hi + j;
            if (gr < n) {
#pragma unroll
                for (int c = 0; c < NC; ++c)
                    C[(size_t)gr * BN + 16 * c + lo] = __float2half(acc[t][c][j]);
            }
        }
    }
}

// ---------------- fused: {streaming scatter (no LDS/atomics)} | {GEMM0} ----------------
__global__ __launch_bounds__(256) void k_s3g0(const int* __restrict__ src,
                                              const int* __restrict__ dst, int E,
                                              const int* __restrict__ rp,
                                              const int* __restrict__ bsum,
                                              const unsigned* __restrict__ pfx_all,
                                              const unsigned char* __restrict__ pos,
                                              int* __restrict__ csr,
                                              const float* __restrict__ feat,
                                              const __half* __restrict__ Wt0,
                                              __half* __restrict__ Hb, int n) {
    const int b = blockIdx.x;
    if (b < NHD) {
        const int perB = ((E + NHD - 1) / NHD + 3) & ~3;
        const int e0 = min(b * perB, E), e1 = min(e0 + perB, E);
        const unsigned* pfx = pfx_all + (size_t)b * HWORDS;
        int i = e0 + threadIdx.x * 4;
        for (; i + 3 < e1; i += 1024) {
            int4 d4 = *(const int4*)(dst + i);
            int4 s4 = *(const int4*)(src + i);
            uchar4 p4 = *(const uchar4*)(pos + i);
#define PLACE(dd, ss, pp)                                                       \
            {                                                                   \
                int sh = ((dd) & 3) * 8;                                        \
                csr[rp[dd] + bsum[(dd) >> 8] +                                  \
                    (int)((pfx[(dd) >> 2] >> sh) & 255u) + (int)(pp)] = (ss);   \
            }
            PLACE(d4.x, s4.x, p4.x) PLACE(d4.y, s4.y, p4.y)
            PLACE(d4.z, s4.z, p4.z) PLACE(d4.w, s4.w, p4.w)
        }
        for (; i < e1; ++i) PLACE(dst[i], src[i], pos[i])
#undef PLACE
    } else {
        gemm_body<128, true>(feat, Wt0, Hb, n, b - NHD);
    }
}

// ---------------- plain GEMM (layers 1,2) ----------------
template <int BN, bool F32A>
__global__ __launch_bounds__(256) void k_gemm(const void* __restrict__ A,
                                              const __half* __restrict__ Wt,
                                              __half* __restrict__ C, int n) {
    gemm_body<BN, F32A>(A, Wt, C, n, blockIdx.x);
}

// ---------------- aggregation D=128: wave/node, half2/lane, masked 8-wide rounds ----
// SSCALE: fold ns[src] per edge (layer 0). Output fp16, pre-scaled by ns[node].
template <bool RELU, bool SSCALE>
__global__ __launch_bounds__(256) void k_agg128h(const __half2* __restrict__ H,  // [N][64]
                                                 const int* __restrict__ rp,
                                                 const int* __restrict__ bsum,
                                                 const int* __restrict__ cs,
                                                 const float* __restrict__ nd,
                                                 const float* __restrict__ ns,
                                                 const float* __restrict__ b,
                                                 __half2* __restrict__ out, int n) {
    const int wid = threadIdx.x >> 6, lane = threadIdx.x & 63;
    const int node = blockIdx.x * 4 + wid;
    if (node >= n) return;
    const int beg = rp[node] + bsum[node >> 8];
    const int end = rp[node + 1] + bsum[(node + 1) >> 8];
    float2 a0 = make_float2(0.f, 0.f), a1 = a0, a2 = a0, a3 = a0;
    float2 a4 = a0, a5 = a0, a6 = a0, a7 = a0;
    for (int e = beg; e < end; e += 8) {
        int s[8];
        float w[8];
#pragma unroll
        for (int j = 0; j < 8; ++j) {
            int idx = e + j;
            int r = (idx < end) ? idx : beg;                  // wave-uniform clamp
            r = __builtin_amdgcn_readfirstlane(r);            // scalarize csr index
            s[j] = cs[r];
            w[j] = (idx < end) ? 1.f : 0.f;
        }
        if (SSCALE) {
#pragma unroll
            for (int j = 0; j < 8; ++j) w[j] *= ns[s[j]];
        }
        float2 v0 = __half22float2(H[(size_t)s[0] * 64 + lane]);
        float2 v1 = __half22float2(H[(size_t)s[1] * 64 + lane]);
        float2 v2 = __half22float2(H[(size_t)s[2] * 64 + lane]);
        float2 v3 = __half22float2(H[(size_t)s[3] * 64 + lane]);
        float2 v4 = __half22float2(H[(size_t)s[4] * 64 + lane]);
        float2 v5 = __half22float2(H[(size_t)s[5] * 64 + lane]);
        float2 v6 = __half22float2(H[(size_t)s[6] * 64 + lane]);
        float2 v7 = __half22float2(H[(size_t)s[7] * 64 + lane]);
        a0.x = fmaf(v0.x, w[0], a0.x); a0.y = fmaf(v0.y, w[0], a0.y);
        a1.x = fmaf(v1.x, w[1], a1.x); a1.y = fmaf(v1.y, w[1], a1.y);
        a2.x = fmaf(v2.x, w[2], a2.x); a2.y = fmaf(v2.y, w[2], a2.y);
        a3.x = fmaf(v3.x, w[3], a3.x); a3.y = fmaf(v3.y, w[3], a3.y);
        a4.x = fmaf(v4.x, w[4], a4.x); a4.y = fmaf(v4.y, w[4], a4.y);
        a5.x = fmaf(v5.x, w[5], a5.x); a5.y = fmaf(v5.y, w[5], a5.y);
        a6.x = fmaf(v6.x, w[6], a6.x); a6.y = fmaf(v6.y, w[6], a6.y);
        a7.x = fmaf(v7.x, w[7], a7.x); a7.y = fmaf(v7.y, w[7], a7.y);
    }
    const float sc = nd[node];
    const float sn = ns[node];
    float2 bb = ((const float2*)b)[lane];
    float ax = ((a0.x + a1.x) + (a2.x + a3.x)) + ((a4.x + a5.x) + (a6.x + a7.x));
    float ay = ((a0.y + a1.y) + (a2.y + a3.y)) + ((a4.y + a5.y) + (a6.y + a7.y));
    float ox = ax * sc + bb.x;
    float oy = ay * sc + bb.y;
    if (RELU) { ox = fmaxf(ox, 0.f); oy = fmaxf(oy, 0.f); }
    ox *= sn; oy *= sn;
    out[(size_t)node * 64 + lane] = __floats2half2_rn(ox, oy);
}

// ---------------- aggregation D=64: wave/node, half/lane, masked 8-wide; f32 out --------
__global__ __launch_bounds__(256) void k_agg64h(const __half* __restrict__ H,  // [N][64]
                                                const int* __restrict__ rp,
                                                const int* __restrict__ bsum,
                                                const int* __restrict__ cs,
                                                const float* __restrict__ nd,
                                                const float* __restrict__ b,
                                                float* __restrict__ out, int n) {
    const int wid = threadIdx.x >> 6, lane = threadIdx.x & 63;
    const int node = blockIdx.x * 4 + wid;
    if (node >= n) return;
    const int beg = rp[node] + bsum[node >> 8];
    const int end = rp[node + 1] + bsum[(node + 1) >> 8];
    float a0 = 0.f, a1 = 0.f, a2 = 0.f, a3 = 0.f;
    float a4 = 0.f, a5 = 0.f, a6 = 0.f, a7 = 0.f;
    for (int e = beg; e < end; e += 8) {
        int s[8];
        float w[8];
#pragma unroll
        for (int j = 0; j < 8; ++j) {
            int idx = e + j;
            int r = (idx < end) ? idx : beg;
            r = __builtin_amdgcn_readfirstlane(r);
            s[j] = cs[r];
            w[j] = (idx < end) ? 1.f : 0.f;
        }
        a0 = fmaf(__half2float(H[(size_t)s[0] * 64 + lane]), w[0], a0);
        a1 = fmaf(__half2float(H[(size_t)s[1] * 64 + lane]), w[1], a1);
        a2 = fmaf(__half2float(H[(size_t)s[2] * 64 + lane]), w[2], a2);
        a3 = fmaf(__half2float(H[(size_t)s[3] * 64 + lane]), w[3], a3);
        a4 = fmaf(__half2float(H[(size_t)s[4] * 64 + lane]), w[4], a4);
        a5 = fmaf(__half2float(H[(size_t)s[5] * 64 + lane]), w[5], a5);
        a6 = fmaf(__half2float(H[(size_t)s[6] * 64 + lane]), w[6], a6);
        a7 = fmaf(__half2float(H[(size_t)s[7] * 64 + lane]), w[7], a7);
    }
    float a = ((a0 + a1) + (a2 + a3)) + ((a4 + a5) + (a6 + a7));
    out[(size_t)node * 64 + lane] = a * nd[node] + b[lane];
}

extern "C" void kernel_launch(void* const* d_in, const int* in_sizes, int n_in,
                              void* d_out, int out_size, void* d_ws, size_t ws_size,
                              hipStream_t stream) {
    const float* feat = (const float*)d_in[0];
    const int* ei = (const int*)d_in[1];
    const float* W0 = (const float*)d_in[2];
    const float* b0 = (const float*)d_in[3];
    const float* W1 = (const float*)d_in[4];
    const float* b1 = (const float*)d_in[5];
    const float* W2 = (const float*)d_in[6];
    const float* b2 = (const float*)d_in[7];
    float* out = (float*)d_out;

    const int N = in_sizes[0] / 128;  // 100000
    const int E = in_sizes[1] / 2;    // 1600000
    const int* src = ei;
    const int* dst = ei + E;
    const int NB = (N + 255) / 256;   // 391 scan blocks (= HWORDS/64)

    // workspace layout (16B-aligned chunks)
    char* w = (char*)d_ws;
    float* norm_src = (float*)w; w += (size_t)N * 4;
    float* norm_dst = (float*)w; w += (size_t)N * 4;
    unsigned* histo_s = (unsigned*)w; w += (size_t)NHS * HWORDS * 4;
    unsigned* histo_d = (unsigned*)w; w += (size_t)NHD * HWORDS * 4;
    int* rp    = (int*)w;        w += ((size_t)(N + 1) * 4 + 15) / 16 * 16;
    int* bsum  = (int*)w;        w += 512 * 4;
    int* csr   = (int*)w;        w += (size_t)E * 4;
    unsigned char* pos = (unsigned char*)w; w += ((size_t)E + 15) / 16 * 16;
    __half* Wt0 = (__half*)w;    w += 128 * 128 * 2;
    __half* Wt1 = (__half*)w;    w += 128 * 128 * 2;
    __half* Wt2 = (__half*)w;    w += 128 * 64 * 2;
    __half* Hb = (__half*)w;     w += (size_t)N * 128 * 2;  // GEMM out (gather src)
    __half* Xb = (__half*)w;     w += (size_t)N * 128 * 2;  // agg out / next GEMM in

    const int GB = (N + 127) / 128;   // 782 GEMM blocks
    const int agg_grid = (N + 3) / 4;

    // CSR build, no global atomics
    k_pre<<<NHS + NHD + 1, 1024, 0, stream>>>(src, dst, E, histo_s, histo_d, pos,
                                              W0, W1, W2, Wt0, Wt1, Wt2);
    k_scan1<<<NB, 256, 0, stream>>>(histo_s, histo_d, rp, bsum, norm_src, norm_dst, N);
    k_scan2<<<1, 512, 0, stream>>>(bsum, NB, rp + N);
    // streaming scatter || GEMM0 (Hb = feat @ W0)
    k_s3g0<<<NHD + GB, 256, 0, stream>>>(src, dst, E, rp, bsum, histo_d, pos, csr,
                                         feat, Wt0, Hb, N);

    // layer 0
    k_agg128h<true, true><<<agg_grid, 256, 0, stream>>>((const __half2*)Hb, rp, bsum, csr,
                                                        norm_dst, norm_src, b0, (__half2*)Xb, N);
    // layer 1
    k_gemm<128, false><<<GB, 256, 0, stream>>>(Xb, Wt1, Hb, N);
    k_agg128h<true, false><<<agg_grid, 256, 0, stream>>>((const __half2*)Hb, rp, bsum, csr,
                                                         norm_dst, norm_src, b1, (__half2*)Xb, N);
    // layer 2 (BN=64, no relu, f32 out)
    k_gemm<64, false><<<GB, 256, 0, stream>>>(Xb, Wt2, Hb, N);
    k_agg64h<<<agg_grid, 256, 0, stream>>>(Hb, rp, bsum, csr, norm_dst, b2, out, N);
}

// Round 21
// 337.529 us; speedup vs baseline: 1.9524x; 1.0263x over previous
//
#include <hip/hip_runtime.h>
#include <hip/hip_fp16.h>

// GCN 3-layer: fp16 intermediates, f32 accum, MFMA GEMMs, zero-global-atomic CSR.
// Round-20 structure; NHS=48/NHD=204 so k_pre's 253 one-block-per-CU blocks fit
// one dispatch round (was 321 -> 2 rounds, 25%-full tail).
// Agg: wave/node, uniform masked 8-wide rounds, scalarized csr index loads.
// Math: (x*ns)@W == (x@W)*ns_row; layer-0 folds ns[src] into the gather (fma),
// later layers pre-scale the agg output by ns (relu(x)*s == relu(x*s), s>0).

typedef _Float16 h8 __attribute__((ext_vector_type(8)));
typedef float f32x4 __attribute__((ext_vector_type(4)));

#define HWORDS 25024   // ceil(100000/4), = 391*64 exactly
#define NHS 48         // src histogram chunks (12 per scan1 wave)
#define NHD 204        // dst histogram chunks (51 per scan1 wave); 48+204+1=253<=256

// ---------------- pre: {48 src hist} | {204 dst hist + pos} | {Wt prep} ----------------
__global__ __launch_bounds__(1024) void k_pre(const int* __restrict__ src,
                                              const int* __restrict__ dst, int E,
                                              unsigned* __restrict__ histo_s,
                                              unsigned* __restrict__ histo_d,
                                              unsigned char* __restrict__ pos,
                                              const float* __restrict__ W0,
                                              const float* __restrict__ W1,
                                              const float* __restrict__ W2,
                                              __half* __restrict__ Wt0,
                                              __half* __restrict__ Wt1,
                                              __half* __restrict__ Wt2) {
    __shared__ unsigned H[HWORDS];
    const int b = blockIdx.x;
    const int tid = threadIdx.x;
    if (b < NHS) {
        // src histogram (no pos)
        const int c = b;
        unsigned* outp = histo_s + (size_t)c * HWORDS;
        for (int i = tid; i < HWORDS; i += 1024) H[i] = 0;
        __syncthreads();
        const int perB = ((E + NHS - 1) / NHS + 3) & ~3;
        const int e0 = min(c * perB, E), e1 = min(e0 + perB, E);
        int i = e0 + tid * 4;
        for (; i + 3 < e1; i += 4096) {
            int4 s4 = *(const int4*)(src + i);
            atomicAdd(&H[s4.x >> 2], 1u << ((s4.x & 3) * 8));
            atomicAdd(&H[s4.y >> 2], 1u << ((s4.y & 3) * 8));
            atomicAdd(&H[s4.z >> 2], 1u << ((s4.z & 3) * 8));
            atomicAdd(&H[s4.w >> 2], 1u << ((s4.w & 3) * 8));
        }
        for (; i < e1; ++i) {
            int s = src[i];
            atomicAdd(&H[s >> 2], 1u << ((s & 3) * 8));
        }
        __syncthreads();
        for (int i2 = tid; i2 < HWORDS; i2 += 1024) outp[i2] = H[i2];
    } else if (b < NHS + NHD) {
        // dst histogram + per-edge rank capture
        const int c = b - NHS;
        unsigned* outp = histo_d + (size_t)c * HWORDS;
        for (int i = tid; i < HWORDS; i += 1024) H[i] = 0;
        __syncthreads();
        const int perB = ((E + NHD - 1) / NHD + 3) & ~3;
        const int e0 = min(c * perB, E), e1 = min(e0 + perB, E);
        int i = e0 + tid * 4;
        for (; i + 3 < e1; i += 4096) {
            int4 d4 = *(const int4*)(dst + i);
            unsigned o0 = atomicAdd(&H[d4.x >> 2], 1u << ((d4.x & 3) * 8));
            unsigned o1 = atomicAdd(&H[d4.y >> 2], 1u << ((d4.y & 3) * 8));
            unsigned o2 = atomicAdd(&H[d4.z >> 2], 1u << ((d4.z & 3) * 8));
            unsigned o3 = atomicAdd(&H[d4.w >> 2], 1u << ((d4.w & 3) * 8));
            uchar4 p4;
            p4.x = (unsigned char)((o0 >> ((d4.x & 3) * 8)) & 255u);
            p4.y = (unsigned char)((o1 >> ((d4.y & 3) * 8)) & 255u);
            p4.z = (unsigned char)((o2 >> ((d4.z & 3) * 8)) & 255u);
            p4.w = (unsigned char)((o3 >> ((d4.w & 3) * 8)) & 255u);
            *(uchar4*)(pos + i) = p4;
        }
        for (; i < e1; ++i) {
            int d = dst[i];
            unsigned o = atomicAdd(&H[d >> 2], 1u << ((d & 3) * 8));
            pos[i] = (unsigned char)((o >> ((d & 3) * 8)) & 255u);
        }
        __syncthreads();
        for (int i2 = tid; i2 < HWORDS; i2 += 1024) outp[i2] = H[i2];
    } else {
        // Wt prep: Wt[n][k] = (half)W[k][n]; 40960 elements
        for (int j = tid; j < 40960; j += 1024) {
            if (j < 16384) {
                int nn = j >> 7, k = j & 127;
                Wt0[j] = __float2half(W0[k * 128 + nn]);
            } else if (j < 32768) {
                int i2 = j - 16384;
                int nn = i2 >> 7, k = i2 & 127;
                Wt1[i2] = __float2half(W1[k * 128 + nn]);
            } else {
                int i2 = j - 32768;
                int nn = i2 >> 7, k = i2 & 127;
                Wt2[i2] = __float2half(W2[k * 64 + nn]);
            }
        }
    }
}

// ---------------- scan1: 4-way parallel dst-prefix transform + norms + block scan ------
__global__ __launch_bounds__(256) void k_scan1(const unsigned* __restrict__ histo_s,
                                               unsigned* __restrict__ histo_d,
                                               int* __restrict__ rp,
                                               int* __restrict__ bsum,
                                               float* __restrict__ ns,
                                               float* __restrict__ nd, int n) {
    __shared__ unsigned qsd[4][64];  // quarter sums (dst), packed bytes
    __shared__ unsigned qss[4][64];  // quarter sums (src)
    __shared__ unsigned di4[64];     // packed deg_i for this block's 256 nodes
    __shared__ unsigned do4[64];     // packed deg_o
    const int tid = threadIdx.x, lane = tid & 63, q = tid >> 6;
    const int w = blockIdx.x * 64 + lane;  // word index (4 nodes); 391*64 == HWORDS
    {
        unsigned s = 0;
#pragma unroll 8
        for (int b = q * (NHD / 4); b < (q + 1) * (NHD / 4); ++b)
            s += histo_d[(size_t)b * HWORDS + w];
        qsd[q][lane] = s;
        unsigned s2 = 0;
#pragma unroll
        for (int b = q * (NHS / 4); b < (q + 1) * (NHS / 4); ++b)
            s2 += histo_s[(size_t)b * HWORDS + w];
        qss[q][lane] = s2;
    }
    __syncthreads();
    if (q == 0) {
        di4[lane] = qsd[0][lane] + qsd[1][lane] + qsd[2][lane] + qsd[3][lane];
        do4[lane] = qss[0][lane] + qss[1][lane] + qss[2][lane] + qss[3][lane];
    }
    // pass 2: write exclusive chunk prefixes with quarter base
    {
        unsigned run = 0;
        for (int k = 0; k < q; ++k) run += qsd[k][lane];
#pragma unroll 8
        for (int b = q * (NHD / 4); b < (q + 1) * (NHD / 4); ++b) {
            unsigned c4 = histo_d[(size_t)b * HWORDS + w];
            histo_d[(size_t)b * HWORDS + w] = run;
            run += c4;  // byte-safe: deg < 256
        }
    }
    __syncthreads();
    int i = blockIdx.x * 256 + tid;
    int v = 0;
    if (i < n) {
        int sh = (tid & 3) * 8;
        v = (di4[tid >> 2] >> sh) & 255;
        int dgo = (do4[tid >> 2] >> sh) & 255;
        nd[i] = rsqrtf((float)max(v, 1));
        ns[i] = rsqrtf((float)max(dgo, 1));
    }
    int x = v;
#pragma unroll
    for (int off = 1; off < 64; off <<= 1) {
        int t = __shfl_up(x, off, 64);
        if (lane >= off) x += t;
    }
    __shared__ int ws[4];
    if (lane == 63) ws[q] = x;
    __syncthreads();
    int wo = 0;
    for (int k = 0; k < q; ++k) wo += ws[k];
    int incl = wo + x;
    if (i < n) rp[i] = incl - v;          // block-local exclusive
    if (tid == 255) bsum[blockIdx.x] = incl;
}

// scan of block sums
__global__ __launch_bounds__(512) void k_scan2(int* __restrict__ bsum, int nb,
                                               int* __restrict__ rpN) {
    __shared__ int s[512];
    const int tid = threadIdx.x;
    int v = (tid < nb) ? bsum[tid] : 0;
    s[tid] = v;
    __syncthreads();
    for (int off = 1; off < 512; off <<= 1) {
        int t = (tid >= off) ? s[tid - off] : 0;
        __syncthreads();
        s[tid] += t;
        __syncthreads();
    }
    if (tid < nb) bsum[tid] = s[tid] - v;  // exclusive block offsets
    if (tid == nb - 1) *rpN = v;           // last block's local total
}

// ---------------- shared GEMM body: C[n,BN](fp16) = A[n,128] @ Wt[BN,128]^T ----------------
// v_mfma_f32_16x16x32_f16; A/B frag = 8 halves at k=8*(lane>>4), row/col=lane&15;
// C/D: col=lane&15, row=(lane>>4)*4+reg (guide m89-verified; round-6 validated).
template <int BN, bool F32A>
__device__ __forceinline__ void gemm_body(const void* __restrict__ Ap,
                                          const __half* __restrict__ Wt,
                                          __half* __restrict__ C, int n, int gb) {
    constexpr int K = 128, BM = 128, LDR = K + 8;  // halves; 272B rows
    __shared__ __half Al[BM * LDR];
    __shared__ __half Bl[BN * LDR];
    const int tid = threadIdx.x;
    const int row0 = gb * BM;
    if (F32A) {
        const float* A = (const float*)Ap;
#pragma unroll
        for (int q = 0; q < 16; ++q) {
            int fi = q * 256 + tid;
            int r = fi >> 5, c = (fi & 31) * 4;
            int gr = row0 + r;
            float4 v = make_float4(0.f, 0.f, 0.f, 0.f);
            if (gr < n) v = *(const float4*)(A + (size_t)gr * K + c);
            __half2 h0 = __floats2half2_rn(v.x, v.y);
            __half2 h1 = __floats2half2_rn(v.z, v.w);
            uint2 pk = make_uint2(*(unsigned*)&h0, *(unsigned*)&h1);
            *(uint2*)&Al[r * LDR + c] = pk;
        }
    } else {
        const __half* A = (const __half*)Ap;
#pragma unroll
        for (int q = 0; q < 8; ++q) {
            int fi = q * 256 + tid;
            int r = fi >> 4, c = (fi & 15) * 8;
            int gr = row0 + r;
            float4 v = make_float4(0.f, 0.f, 0.f, 0.f);
            if (gr < n) v = *(const float4*)(A + (size_t)gr * K + c);
            *(float4*)&Al[r * LDR + c] = v;
        }
    }
#pragma unroll
    for (int q = 0; q < BN / 16; ++q) {
        int fi = q * 256 + tid;
        int r = fi >> 4, c = (fi & 15) * 8;
        *(float4*)&Bl[r * LDR + c] = *(const float4*)(Wt + (size_t)r * K + c);
    }
    __syncthreads();
    const int wid = tid >> 6, lane = tid & 63;
    const int lo = lane & 15, hi = lane >> 4;
    constexpr int NC = BN / 16;
    f32x4 acc[2][NC];
#pragma unroll
    for (int t = 0; t < 2; ++t)
#pragma unroll
        for (int c = 0; c < NC; ++c) acc[t][c] = (f32x4){0.f, 0.f, 0.f, 0.f};
#pragma unroll
    for (int kc = 0; kc < 4; ++kc) {
        h8 aF[2];
#pragma unroll
        for (int t = 0; t < 2; ++t)
            aF[t] = *(const h8*)&Al[(32 * wid + 16 * t + lo) * LDR + 32 * kc + 8 * hi];
#pragma unroll
        for (int c = 0; c < NC; ++c) {
            h8 bF = *(const h8*)&Bl[(16 * c + lo) * LDR + 32 * kc + 8 * hi];
#pragma unroll
            for (int t = 0; t < 2; ++t)
                acc[t][c] = __builtin_amdgcn_mfma_f32_16x16x32_f16(aF[t], bF, acc[t][c], 0, 0, 0);
        }
    }
#pragma unroll
    for (int t = 0; t < 2; ++t) {
#pragma unroll
        for (int j = 0; j < 4; ++j) {
            int gr = row0 + 32 * wid + 16 * t + 4 * hi + j;
            if (gr < n) {
#pragma unroll
                for (int c = 0; c < NC; ++c)
                    C[(size_t)gr * BN + 16 * c + lo] = __float2half(acc[t][c][j]);
            }
        }
    }
}

// ---------------- fused: {streaming scatter (no LDS/atomics)} | {GEMM0} ----------------
__global__ __launch_bounds__(256) void k_s3g0(const int* __restrict__ src,
                                              const int* __restrict__ dst, int E,
                                              const int* __restrict__ rp,
                                              const int* __restrict__ bsum,
                                              const unsigned* __restrict__ pfx_all,
                                              const unsigned char* __restrict__ pos,
                                              int* __restrict__ csr,
                                              const float* __restrict__ feat,
                                              const __half* __restrict__ Wt0,
                                              __half* __restrict__ Hb, int n) {
    const int b = blockIdx.x;
    if (b < NHD) {
        const int perB = ((E + NHD - 1) / NHD + 3) & ~3;
        const int e0 = min(b * perB, E), e1 = min(e0 + perB, E);
        const unsigned* pfx = pfx_all + (size_t)b * HWORDS;
        int i = e0 + threadIdx.x * 4;
        for (; i + 3 < e1; i += 1024) {
            int4 d4 = *(const int4*)(dst + i);
            int4 s4 = *(const int4*)(src + i);
            uchar4 p4 = *(const uchar4*)(pos + i);
#define PLACE(dd, ss, pp)                                                       \
            {                                                                   \
                int sh = ((dd) & 3) * 8;                                        \
                csr[rp[dd] + bsum[(dd) >> 8] +                                  \
                    (int)((pfx[(dd) >> 2] >> sh) & 255u) + (int)(pp)] = (ss);   \
            }
            PLACE(d4.x, s4.x, p4.x) PLACE(d4.y, s4.y, p4.y)
            PLACE(d4.z, s4.z, p4.z) PLACE(d4.w, s4.w, p4.w)
        }
        for (; i < e1; ++i) PLACE(dst[i], src[i], pos[i])
#undef PLACE
    } else {
        gemm_body<128, true>(feat, Wt0, Hb, n, b - NHD);
    }
}

// ---------------- plain GEMM (layers 1,2) ----------------
template <int BN, bool F32A>
__global__ __launch_bounds__(256) void k_gemm(const void* __restrict__ A,
                                              const __half* __restrict__ Wt,
                                              __half* __restrict__ C, int n) {
    gemm_body<BN, F32A>(A, Wt, C, n, blockIdx.x);
}

// ---------------- aggregation D=128: wave/node, half2/lane, masked 8-wide rounds ----
// SSCALE: fold ns[src] per edge (layer 0). Output fp16, pre-scaled by ns[node].
template <bool RELU, bool SSCALE>
__global__ __launch_bounds__(256) void k_agg128h(const __half2* __restrict__ H,  // [N][64]
                                                 const int* __restrict__ rp,
                                                 const int* __restrict__ bsum,
                                                 const int* __restrict__ cs,
                                                 const float* __restrict__ nd,
                                                 const float* __restrict__ ns,
                                                 const float* __restrict__ b,
                                                 __half2* __restrict__ out, int n) {
    const int wid = threadIdx.x >> 6, lane = threadIdx.x & 63;
    const int node = blockIdx.x * 4 + wid;
    if (node >= n) return;
    const int beg = rp[node] + bsum[node >> 8];
    const int end = rp[node + 1] + bsum[(node + 1) >> 8];
    float2 a0 = make_float2(0.f, 0.f), a1 = a0, a2 = a0, a3 = a0;
    float2 a4 = a0, a5 = a0, a6 = a0, a7 = a0;
    for (int e = beg; e < end; e += 8) {
        int s[8];
        float w[8];
#pragma unroll
        for (int j = 0; j < 8; ++j) {
            int idx = e + j;
            int r = (idx < end) ? idx : beg;                  // wave-uniform clamp
            r = __builtin_amdgcn_readfirstlane(r);            // scalarize csr index
            s[j] = cs[r];
            w[j] = (idx < end) ? 1.f : 0.f;
        }
        if (SSCALE) {
#pragma unroll
            for (int j = 0; j < 8; ++j) w[j] *= ns[s[j]];
        }
        float2 v0 = __half22float2(H[(size_t)s[0] * 64 + lane]);
        float2 v1 = __half22float2(H[(size_t)s[1] * 64 + lane]);
        float2 v2 = __half22float2(H[(size_t)s[2] * 64 + lane]);
        float2 v3 = __half22float2(H[(size_t)s[3] * 64 + lane]);
        float2 v4 = __half22float2(H[(size_t)s[4] * 64 + lane]);
        float2 v5 = __half22float2(H[(size_t)s[5] * 64 + lane]);
        float2 v6 = __half22float2(H[(size_t)s[6] * 64 + lane]);
        float2 v7 = __half22float2(H[(size_t)s[7] * 64 + lane]);
        a0.x = fmaf(v0.x, w[0], a0.x); a0.y = fmaf(v0.y, w[0], a0.y);
        a1.x = fmaf(v1.x, w[1], a1.x); a1.y = fmaf(v1.y, w[1], a1.y);
        a2.x = fmaf(v2.x, w[2], a2.x); a2.y = fmaf(v2.y, w[2], a2.y);
        a3.x = fmaf(v3.x, w[3], a3.x); a3.y = fmaf(v3.y, w[3], a3.y);
        a4.x = fmaf(v4.x, w[4], a4.x); a4.y = fmaf(v4.y, w[4], a4.y);
        a5.x = fmaf(v5.x, w[5], a5.x); a5.y = fmaf(v5.y, w[5], a5.y);
        a6.x = fmaf(v6.x, w[6], a6.x); a6.y = fmaf(v6.y, w[6], a6.y);
        a7.x = fmaf(v7.x, w[7], a7.x); a7.y = fmaf(v7.y, w[7], a7.y);
    }
    const float sc = nd[node];
    const float sn = ns[node];
    float2 bb = ((const float2*)b)[lane];
    float ax = ((a0.x + a1.x) + (a2.x + a3.x)) + ((a4.x + a5.x) + (a6.x + a7.x));
    float ay = ((a0.y + a1.y) + (a2.y + a3.y)) + ((a4.y + a5.y) + (a6.y + a7.y));
    float ox = ax * sc + bb.x;
    float oy = ay * sc + bb.y;
    if (RELU) { ox = fmaxf(ox, 0.f); oy = fmaxf(oy, 0.f); }
    ox *= sn; oy *= sn;
    out[(size_t)node * 64 + lane] = __floats2half2_rn(ox, oy);
}

// ---------------- aggregation D=64: wave/node, half/lane, masked 8-wide; f32 out --------
__global__ __launch_bounds__(256) void k_agg64h(const __half* __restrict__ H,  // [N][64]
                                                const int* __restrict__ rp,
                                                const int* __restrict__ bsum,
                                                const int* __restrict__ cs,
                                                const float* __restrict__ nd,
                                                const float* __restrict__ b,
                                                float* __restrict__ out, int n) {
    const int wid = threadIdx.x >> 6, lane = threadIdx.x & 63;
    const int node = blockIdx.x * 4 + wid;
    if (node >= n) return;
    const int beg = rp[node] + bsum[node >> 8];
    const int end = rp[node + 1] + bsum[(node + 1) >> 8];
    float a0 = 0.f, a1 = 0.f, a2 = 0.f, a3 = 0.f;
    float a4 = 0.f, a5 = 0.f, a6 = 0.f, a7 = 0.f;
    for (int e = beg; e < end; e += 8) {
        int s[8];
        float w[8];
#pragma unroll
        for (int j = 0; j < 8; ++j) {
            int idx = e + j;
            int r = (idx < end) ? idx : beg;
            r = __builtin_amdgcn_readfirstlane(r);
            s[j] = cs[r];
            w[j] = (idx < end) ? 1.f : 0.f;
        }
        a0 = fmaf(__half2float(H[(size_t)s[0] * 64 + lane]), w[0], a0);
        a1 = fmaf(__half2float(H[(size_t)s[1] * 64 + lane]), w[1], a1);
        a2 = fmaf(__half2float(H[(size_t)s[2] * 64 + lane]), w[2], a2);
        a3 = fmaf(__half2float(H[(size_t)s[3] * 64 + lane]), w[3], a3);
        a4 = fmaf(__half2float(H[(size_t)s[4] * 64 + lane]), w[4], a4);
        a5 = fmaf(__half2float(H[(size_t)s[5] * 64 + lane]), w[5], a5);
        a6 = fmaf(__half2float(H[(size_t)s[6] * 64 + lane]), w[6], a6);
        a7 = fmaf(__half2float(H[(size_t)s[7] * 64 + lane]), w[7], a7);
    }
    float a = ((a0 + a1) + (a2 + a3)) + ((a4 + a5) + (a6 + a7));
    out[(size_t)node * 64 + lane] = a * nd[node] + b[lane];
}

extern "C" void kernel_launch(void* const* d_in, const int* in_sizes, int n_in,
                              void* d_out, int out_size, void* d_ws, size_t ws_size,
                              hipStream_t stream) {
    const float* feat = (const float*)d_in[0];
    const int* ei = (const int*)d_in[1];
    const float* W0 = (const float*)d_in[2];
    const float* b0 = (const float*)d_in[3];
    const float* W1 = (const float*)d_in[4];
    const float* b1 = (const float*)d_in[5];
    const float* W2 = (const float*)d_in[6];
    const float* b2 = (const float*)d_in[7];
    float* out = (float*)d_out;

    const int N = in_sizes[0] / 128;  // 100000
    const int E = in_sizes[1] / 2;    // 1600000
    const int* src = ei;
    const int* dst = ei + E;
    const int NB = (N + 255) / 256;   // 391 scan blocks (= HWORDS/64)

    // workspace layout (16B-aligned chunks)
    char* w = (char*)d_ws;
    float* norm_src = (float*)w; w += (size_t)N * 4;
    float* norm_dst = (float*)w; w += (size_t)N * 4;
    unsigned* histo_s = (unsigned*)w; w += (size_t)NHS * HWORDS * 4;
    unsigned* histo_d = (unsigned*)w; w += (size_t)NHD * HWORDS * 4;
    int* rp    = (int*)w;        w += ((size_t)(N + 1) * 4 + 15) / 16 * 16;
    int* bsum  = (int*)w;        w += 512 * 4;
    int* csr   = (int*)w;        w += (size_t)E * 4;
    unsigned char* pos = (unsigned char*)w; w += ((size_t)E + 15) / 16 * 16;
    __half* Wt0 = (__half*)w;    w += 128 * 128 * 2;
    __half* Wt1 = (__half*)w;    w += 128 * 128 * 2;
    __half* Wt2 = (__half*)w;    w += 128 * 64 * 2;
    __half* Hb = (__half*)w;     w += (size_t)N * 128 * 2;  // GEMM out (gather src)
    __half* Xb = (__half*)w;     w += (size_t)N * 128 * 2;  // agg out / next GEMM in

    const int GB = (N + 127) / 128;   // 782 GEMM blocks
    const int agg_grid = (N + 3) / 4;

    // CSR build, no global atomics (253 blocks -> single dispatch round)
    k_pre<<<NHS + NHD + 1, 1024, 0, stream>>>(src, dst, E, histo_s, histo_d, pos,
                                              W0, W1, W2, Wt0, Wt1, Wt2);
    k_scan1<<<NB, 256, 0, stream>>>(histo_s, histo_d, rp, bsum, norm_src, norm_dst, N);
    k_scan2<<<1, 512, 0, stream>>>(bsum, NB, rp + N);
    // streaming scatter || GEMM0 (Hb = feat @ W0)
    k_s3g0<<<NHD + GB, 256, 0, stream>>>(src, dst, E, rp, bsum, histo_d, pos, csr,
                                         feat, Wt0, Hb, N);

    // layer 0
    k_agg128h<true, true><<<agg_grid, 256, 0, stream>>>((const __half2*)Hb, rp, bsum, csr,
                                                        norm_dst, norm_src, b0, (__half2*)Xb, N);
    // layer 1
    k_gemm<128, false><<<GB, 256, 0, stream>>>(Xb, Wt1, Hb, N);
    k_agg128h<true, false><<<agg_grid, 256, 0, stream>>>((const __half2*)Hb, rp, bsum, csr,
                                                         norm_dst, norm_src, b1, (__half2*)Xb, N);
    // layer 2 (BN=64, no relu, f32 out)
    k_gemm<64, false><<<GB, 256, 0, stream>>>(Xb, Wt2, Hb, N);
    k_agg64h<<<agg_grid, 256, 0, stream>>>(Hb, rp, bsum, csr, norm_dst, b2, out, N);
}